// Round 8
// baseline (1591.584 us; speedup 1.0000x reference)
//
#include <hip/hip_runtime.h>
#include <cstdint>

#define BB 16
#define NN 8192
#define MM 1024
#define KNN 32
#define CIN 64
#define HID 64
#define OCH 128

// workspace float offsets
#define KNN_OFF   0u          // 524288 ints
#define SUM1_OFF  524288u     // 2048
#define SUM2_OFF  526336u     // 4096
#define A1_OFF    530432u     // (unused since R7; kept for layout stability)
#define D1_OFF    531456u
#define A2_OFF    532480u
#define D2_OFF    534528u
#define W2B_OFF   536576u     // 4096 floats = 8192 bf16 (w2 pre-converted)
#define W1B_OFF   540672u     // 3072 floats = 6144 bf16 (w1 padded 67->96, bf16)
#define Y1_OFF    543744u     // y1 bf16: 16384 tiles x 1024 floats (2048 bf16)
#define PTS4_OFF  Y1_OFF      // 131072 float4 (dead once conv1 runs; knn before conv1)
#define FEAT16_OFF (Y1_OFF + 16777216u)  // feat bf16: 4194304 floats (8M bf16)

typedef unsigned long long u64;
typedef float f32x4 __attribute__((ext_vector_type(4)));
typedef float f32x2 __attribute__((ext_vector_type(2)));
typedef short bf16x8 __attribute__((ext_vector_type(8)));

__device__ __forceinline__ unsigned short f2bf(float f) {
  union { float f; unsigned u; } v; v.f = f;
  unsigned r = v.u + 0x7FFFu + ((v.u >> 16) & 1u);   // RNE
  return (unsigned short)(r >> 16);
}

__device__ __forceinline__ float bf2f(unsigned short u) {
  return __uint_as_float((unsigned)u << 16);
}

// ---------------- K0: zero stats + pts4 + w2/w1/feat -> bf16 ------------------
// R7: feat pre-converted to bf16 here (same RNE bits conv1 used to produce
// in-kernel) so conv1's gather halves in bytes and sheds its f2bf work.
__global__ __launch_bounds__(256) void k0_init(const float* __restrict__ xyz,
                                               const float* __restrict__ feat,
                                               const float* __restrict__ w1,
                                               const float* __restrict__ w2,
                                               float* __restrict__ ws) {
  int t = blockIdx.x * 256 + threadIdx.x;
  if (t < 12288) ws[SUM1_OFF + t] = 0.0f;
  if (t < 4096) {   // w2: 128x64 f32 -> bf16 pairs (RNE)
    unsigned lo = f2bf(w2[2 * t]);
    unsigned hi = f2bf(w2[2 * t + 1]);
    ((unsigned*)(ws + W2B_OFF))[t] = lo | (hi << 16);
  }
  if (t < 6144) {   // w1b[n][kk]: kk 0..2 = w1[n][0..2]; kk==3 dummy 0;
                    // kk 4..67 = w1[n][kk-1]; kk 68..95 = 0 (K pad for MFMA)
    int n = t / 96, kk = t % 96;
    float val = 0.0f;
    if (kk < 3) val = w1[n * 67 + kk];
    else if (kk >= 4 && kk < 68) val = w1[n * 67 + kk - 1];
    ((unsigned short*)(ws + W1B_OFF))[t] = f2bf(val);
  }
  if (t < BB * NN) {
    #pragma clang fp contract(off)
    float x = xyz[(size_t)t * 3], y = xyz[(size_t)t * 3 + 1], z = xyz[(size_t)t * 3 + 2];
    ((float4*)(ws + PTS4_OFF))[t] = make_float4(x, y, z, (x * x + y * y) + z * z);
  }
  if (t < 4194304) {  // feat f32 -> bf16 pairs (16*8192*64 / 2 u32s)
    float2 fv = *(const float2*)(feat + 2 * (size_t)t);
    unsigned lo = f2bf(fv.x), hi = f2bf(fv.y);
    ((unsigned*)(ws + FEAT16_OFF))[t] = lo | (hi << 16);
  }
}

// DPP u64 max-reduction across a wave; full max lands in lane 63.
__device__ __forceinline__ u64 wave_max_u64(u64 v) {
  #define DPP_RND(ctrl, rm)                                                     \
  {                                                                             \
    int lo_ = __builtin_amdgcn_update_dpp(0, (int)(unsigned)(v & 0xFFFFFFFFull),\
                                          ctrl, rm, 0xf, true);                 \
    int hi_ = __builtin_amdgcn_update_dpp(0, (int)(unsigned)(v >> 32),          \
                                          ctrl, rm, 0xf, true);                 \
    u64 o_ = ((u64)(unsigned)hi_ << 32) | (unsigned)lo_;                        \
    v = o_ > v ? o_ : v;                                                        \
  }
  DPP_RND(0x111, 0xf)  // row_shr:1
  DPP_RND(0x112, 0xf)  // row_shr:2
  DPP_RND(0x114, 0xf)  // row_shr:4
  DPP_RND(0x118, 0xf)  // row_shr:8
  DPP_RND(0x142, 0xa)  // row_bcast:15 -> rows 1,3
  DPP_RND(0x143, 0xc)  // row_bcast:31 -> rows 2,3
  #undef DPP_RND
  return v;
}

// ---------------- K1: FPS — 256 thr (4 waves, 1/SIMD) -------------------------
// R7 latency restructure (selection semantics preserved bit-for-bit):
//  (1) deferred argmax: in-loop value-only fmax chain (fuses to v_max3_f32);
//      index recovered post-loop via dm_j == best match + min-j tree. fmax
//      returns one of its inputs, so best is bitwise some dm_j; min-j among
//      equals == "strict >, ascending scan" tie-break. Removes the 16-deep
//      cmp->sel->sel chain (~190cy exposed).
//  (2) no-atomic cross-wave combine: lane63 plain-stores its reduced key into
//      wred[step&1][w] (parity = WAR-safe across single barrier); all threads
//      read 4 keys + 3 u64 max-selects -> far computed LOCALLY (drops the
//      dependent post-barrier slots re-read, ~120cy). tid0 archives the key
//      to slots[step] (off-path) for the deferred centroid replay.
__global__ __launch_bounds__(256) void fps_kernel(const float* __restrict__ xyz,
                                                  float* __restrict__ cent) {
  #pragma clang fp contract(off)
  __shared__ float4 sp4[NN];     // 128 KB
  __shared__ u64 slots[MM];      // 8 KB (replay archive only)
  __shared__ u64 wred[2][4];     // [parity][wave]
  const int b = blockIdx.x, tid = threadIdx.x;
  const int w = tid >> 6;
  const float* xp = xyz + (size_t)b * NN * 3;
  f32x2 px[16], py[16], pz[16];
  float dist0[16], dist1[16];
  #pragma unroll
  for (int i = 0; i < 16; ++i) {
    int n0 = tid + (2 * i) * 256, n1 = tid + (2 * i + 1) * 256;
    float x0 = xp[n0 * 3], y0 = xp[n0 * 3 + 1], z0 = xp[n0 * 3 + 2];
    float x1 = xp[n1 * 3], y1 = xp[n1 * 3 + 1], z1 = xp[n1 * 3 + 2];
    px[i] = (f32x2){x0, x1}; py[i] = (f32x2){y0, y1}; pz[i] = (f32x2){z0, z1};
    sp4[n0] = make_float4(x0, y0, z0, 0.0f);
    sp4[n1] = make_float4(x1, y1, z1, 0.0f);
    dist0[i] = 1e10f; dist1[i] = 1e10f;
  }
  __syncthreads();
  int far = 0;
  for (int step = 0; step < MM; ++step) {
    float4 c4 = sp4[far];
    f32x2 cx = (f32x2){c4.x, c4.x}, cy = (f32x2){c4.y, c4.y}, cz = (f32x2){c4.z, c4.z};
    float best = -1.0f;
    #pragma unroll
    for (int i = 0; i < 16; ++i) {
      f32x2 dx = px[i] - cx, dy = py[i] - cy, dz = pz[i] - cz;
      f32x2 d = (dx * dx + dy * dy) + dz * dz;   // np: left-assoc, no fma (per slot)
      float dm0 = fminf(dist0[i], d.x);
      float dm1 = fminf(dist1[i], d.y);
      dist0[i] = dm0; dist1[i] = dm1;
      best = fmaxf(fmaxf(best, dm0), dm1);       // value-only; index deferred
    }
    // post-scan: lowest j with dm_j == best (j = 2i for slot0, 2i+1 for slot1;
    // n = tid + j*256 increasing in j -> lowest-n tie-break preserved)
    unsigned sel[16];
    #pragma unroll
    for (int i = 0; i < 16; ++i) {
      unsigned s0 = (dist0[i] == best) ? (unsigned)(2 * i) : 63u;
      unsigned s1 = (dist1[i] == best) ? (unsigned)(2 * i + 1) : 63u;
      sel[i] = s0 < s1 ? s0 : s1;
    }
    #pragma unroll
    for (int st = 8; st >= 1; st >>= 1)
      #pragma unroll
      for (int i = 0; i < st; ++i)
        sel[i] = sel[i] < sel[i + st] ? sel[i] : sel[i + st];
    int bi = tid + (int)(sel[0] << 8);
    u64 key = ((u64)__float_as_uint(best) << 32) | (unsigned)(8191 - bi);
    key = wave_max_u64(key);
    const int p = step & 1;
    if ((tid & 63) == 63) wred[p][w] = key;      // plain store, no atomic
    __syncthreads();
    u64 k0 = wred[p][0], k1 = wred[p][1], k2 = wred[p][2], k3 = wred[p][3];
    u64 m01 = k0 > k1 ? k0 : k1;
    u64 m23 = k2 > k3 ? k2 : k3;
    u64 bk = m01 > m23 ? m01 : m23;              // commutative max, tie-free keys
    if (tid == 0) slots[step] = bk;              // archive for replay (off-path)
    far = 8191 - (int)(unsigned)(bk & 0xFFFFFFFFull);
  }
  __syncthreads();   // make tid0's slots[] archive visible to all
  // replay: cent[0] = start point 0; cent[s] = winner of step s-1.
  float* co = cent + (size_t)b * MM * 3;
  for (int s = tid; s < MM; s += 256) {
    int fs = (s == 0) ? 0 : (8191 - (int)(unsigned)(slots[s - 1] & 0xFFFFFFFFull));
    float4 c = sp4[fs];
    co[s * 3 + 0] = c.x; co[s * 3 + 1] = c.y; co[s * 3 + 2] = c.z;
  }
}

// ---------------- K2: kNN — 8-way N-split, bank-free buffers, tree merge ------
__global__ __launch_bounds__(512) void knn_kernel(const float4* __restrict__ pts4,
                                                  const float* __restrict__ cent,
                                                  int* __restrict__ knnout) {
  #pragma clang fp contract(off)
  __shared__ __align__(16) char smem[65536];
  unsigned* blo = (unsigned*)smem;              // [16][512] cand idx (bank-free)
  unsigned* bhi = (unsigned*)(smem + 32768);    // [16][512] cand key-hi
  u64* marea = (u64*)smem;                      // 4 areas x [32][64]; aliases buffers
                                                // AFTER the post-scan barrier (R5 lesson)
  const int tid = threadIdx.x;
  const int lane = tid & 63;
  const int w = tid >> 6;          // wave id = N-octant
  const int b = blockIdx.x >> 4;
  const int m = ((blockIdx.x & 15) << 6) + lane;
  const float* cp = cent + ((size_t)b * MM + m) * 3;
  float cx = cp[0], cy = cp[1], cz = cp[2];
  float cn2 = (cx * cx + cy * cy) + cz * cz;
  u64 key[32];
  {
    u64 initk = ((u64)(__float_as_uint(3e38f) ^ 0x80000000u) << 32) | 0xFFFFFFFFull;
    #pragma unroll
    for (int j = 0; j < 32; ++j) key[j] = initk;
  }
  float kthf = 3e38f;

  auto insert = [&](u64 cand) {   // ascending sorted insert, static indexing only
    bool cprev = false; u64 kprev = 0;
    #pragma unroll
    for (int j = 0; j < 32; ++j) {
      bool cj = cand < key[j];
      u64 cur = key[j];
      u64 nv = cj ? cand : cur;
      key[j] = cprev ? kprev : nv;
      cprev = cj; kprev = cur;
    }
    unsigned hb = (unsigned)(key[31] >> 32);
    unsigned ob = (hb & 0x80000000u) ? (hb ^ 0x80000000u) : ~hb;
    kthf = __uint_as_float(ob);
  };

  int cnt = 0;
  auto flush = [&]() {
    int mc = cnt;
    #pragma unroll
    for (int off = 1; off < 64; off <<= 1) { int o = __shfl_xor(mc, off); mc = o > mc ? o : mc; }
    for (int i = 0; i < mc; ++i) {
      u64 cand = ((u64)bhi[i * 512 + tid] << 32) | blo[i * 512 + tid];
      if (i < cnt && cand < key[31]) insert(cand);   // exact (d2,idx) lex decision
    }
    cnt = 0;
  };

  const int nbase = __builtin_amdgcn_readfirstlane(w * 1024);  // force SGPR -> s_load path
  const float4* pb = pts4 + (size_t)b * NN + nbase;
  for (int n0 = 0; n0 < 1024; n0 += 8) {
    #pragma unroll
    for (int j = 0; j < 8; ++j) {
      int n = n0 + j;
      float4 p = pb[n];
      float dot = fmaf(cz, p.z, fmaf(cy, p.y, cx * p.x));  // verified np-exact form
      float d2 = (cn2 + p.w) - 2.0f * dot;                  // separate ufunc ops
      if (d2 <= kthf) {                                     // exact re-check at insert
        unsigned db = __float_as_uint(d2);
        unsigned fk = db ^ (((int)db < 0) ? 0xFFFFFFFFu : 0x80000000u);
        blo[cnt * 512 + tid] = (unsigned)(nbase + n);
        bhi[cnt * 512 + tid] = fk;
        cnt++;
      }
    }
    if (__ballot(cnt >= 9)) flush();   // cap 16: <=8 carried + <=8 new
  }
  flush();
  __syncthreads();   // all waves done scanning; buffers dead -> marea aliasing safe

  auto publish = [&](int a) {
    u64* ap = marea + a * 2048;
    #pragma unroll
    for (int j = 0; j < 32; ++j) ap[j * 64 + lane] = key[j];   // [j][lane]: bank-free
  };
  auto merge_from = [&](int a) {
    u64* ap = marea + a * 2048;
    for (int j = 0; j < 32; ++j) {
      u64 cand = ap[j * 64 + lane];
      if (cand < key[31]) insert(cand);    // exact pairwise min-32 merge
    }
  };
  // tree merge 8->4->2->1 (all barriers at top level)
  if (w & 1) publish(w >> 1);
  __syncthreads();
  if (!(w & 1)) merge_from(w >> 1);
  __syncthreads();
  if (w == 2) publish(0);
  if (w == 6) publish(1);
  __syncthreads();
  if (w == 0) merge_from(0);
  if (w == 4) merge_from(1);
  __syncthreads();
  if (w == 4) publish(0);
  __syncthreads();
  if (w == 0) {
    merge_from(0);
    int* op = knnout + ((size_t)b * MM + m) * KNN;
    #pragma unroll
    for (int j = 0; j < 32; ++j) op[j] = (int)(key[j] & 0xFFFFFFFFull);
  }
}

// ---------------- K3: conv1 via MFMA + fused GN1 stats, bf16 y1/feat ----------
// A-frag: A[m=lane&15][k=quad*8+j] from LDS gf[32][104] bf16
// B-frag: B[k][n=lane&15] = w1b[n][k] (padded K layout; zeros kill pad lanes)
// D:      D[m=quad*4+reg][n=lane&15]  (verified m89/m91 mapping, same as conv2)
// R7: feat gathered as pre-converted bf16 (identical bits; half the gather
// bytes, no f2bf in staging). GN1 stats still accumulated from f32 z.
__global__ __launch_bounds__(256) void conv1_kernel(const float* __restrict__ xyz,
                                                    const unsigned short* __restrict__ feat16,
                                                    const float* __restrict__ cent,
                                                    const int* __restrict__ knn,
                                                    const unsigned short* __restrict__ w1b,
                                                    const float* __restrict__ b1,
                                                    float* __restrict__ y1,
                                                    float* __restrict__ sums1) {
  __shared__ __align__(16) unsigned short gsm[4][32 * 104];
  __shared__ float s1acc[64], q1acc[64];
  const int tid = threadIdx.x, lane = tid & 63, w = tid >> 6;
  const int wid = blockIdx.x * 4 + w;           // (b,m) pair 0..16383
  const int b = wid >> 10;
  unsigned short* gf = gsm[w];

  if (tid < 64) { s1acc[tid] = 0.0f; q1acc[tid] = 0.0f; }
  __syncthreads();

  int idxv = 0;
  if (lane < 32) idxv = knn[(size_t)wid * 32 + lane];

  // zero K-pad [64..96) per row (feat phase below overwrites [64..67])
  {
    int row = lane >> 1, h = (lane & 1) * 16;
    ushort4 z4 = {0, 0, 0, 0};
    *(ushort4*)(gf + row * 104 + 64 + h + 0)  = z4;
    *(ushort4*)(gf + row * 104 + 64 + h + 4)  = z4;
    *(ushort4*)(gf + row * 104 + 64 + h + 8)  = z4;
    *(ushort4*)(gf + row * 104 + 64 + h + 12) = z4;
  }
  // delta rows (lanes 0..31): gf[r][0..2] = xyz[idx]-cent, gf[r][3] = dummy 0
  const float* cp = cent + (size_t)wid * 3;
  float ccx = cp[0], ccy = cp[1], ccz = cp[2];
  if (lane < 32) {
    const float* pp = xyz + ((size_t)b * NN + idxv) * 3;
    ushort4 dv;
    dv.x = f2bf(pp[0] - ccx); dv.y = f2bf(pp[1] - ccy); dv.z = f2bf(pp[2] - ccz);
    dv.w = 0;
    *(ushort4*)(gf + lane * 104) = dv;
  }
  // feat: 32 rows x 128B bf16, gathered as 16B ushort8 units (4 iters/lane)
  const unsigned short* fb = feat16 + (size_t)b * NN * 64;
  #pragma unroll
  for (int i = 0; i < 4; ++i) {
    int v = i * 64 + lane;          // 0..255 units of 16B
    int row = v >> 3, part = v & 7;
    int ridx = __shfl(idxv, row);
    uint4 fv = *(const uint4*)(fb + (size_t)ridx * 64 + part * 8);
    *(uint2*)(gf + row * 104 + 4 + part * 8)     = make_uint2(fv.x, fv.y);
    *(uint2*)(gf + row * 104 + 4 + part * 8 + 4) = make_uint2(fv.z, fv.w);
  }
  __builtin_amdgcn_s_waitcnt(0);
  __builtin_amdgcn_wave_barrier();

  const int quad = lane >> 4, lr = lane & 15;
  bf16x8 bw[4][3];
  float b1v[4];
  #pragma unroll
  for (int nt = 0; nt < 4; ++nt) {
    #pragma unroll
    for (int ks = 0; ks < 3; ++ks)
      bw[nt][ks] = *(const bf16x8*)(w1b + (size_t)(nt * 16 + lr) * 96 + ks * 32 + quad * 8);
    b1v[nt] = b1[nt * 16 + lr];
  }
  f32x4 acc[2][4];
  #pragma unroll
  for (int mt = 0; mt < 2; ++mt)
    #pragma unroll
    for (int nt = 0; nt < 4; ++nt)
      acc[mt][nt] = (f32x4){0.f, 0.f, 0.f, 0.f};
  #pragma unroll
  for (int ks = 0; ks < 3; ++ks) {
    bf16x8 a0 = *(const bf16x8*)(gf + (0 + lr) * 104 + ks * 32 + quad * 8);
    bf16x8 a1 = *(const bf16x8*)(gf + (16 + lr) * 104 + ks * 32 + quad * 8);
    #pragma unroll
    for (int nt = 0; nt < 4; ++nt) {
      acc[0][nt] = __builtin_amdgcn_mfma_f32_16x16x32_bf16(a0, bw[nt][ks], acc[0][nt], 0, 0, 0);
      acc[1][nt] = __builtin_amdgcn_mfma_f32_16x16x32_bf16(a1, bw[nt][ks], acc[1][nt], 0, 0, 0);
    }
  }
  unsigned short* yo16 = (unsigned short*)(y1 + (size_t)wid * 1024);
  float s_nt[4] = {0.f, 0.f, 0.f, 0.f};
  float q_nt[4] = {0.f, 0.f, 0.f, 0.f};
  #pragma unroll
  for (int mt = 0; mt < 2; ++mt)
    #pragma unroll
    for (int rg = 0; rg < 4; ++rg) {
      int row = mt * 16 + quad * 4 + rg;
      #pragma unroll
      for (int nt = 0; nt < 4; ++nt) {
        float z = acc[mt][nt][rg] + b1v[nt];
        yo16[row * 64 + nt * 16 + lr] = f2bf(z);
        s_nt[nt] += z;
        q_nt[nt] = fmaf(z, z, q_nt[nt]);
      }
    }
  // quad reduce (lanes lr, lr+16, lr+32, lr+48 hold the 4 row-quarters of ch c)
  #pragma unroll
  for (int nt = 0; nt < 4; ++nt) {
    float s = s_nt[nt], q = q_nt[nt];
    s += __shfl_xor(s, 16); s += __shfl_xor(s, 32);
    q += __shfl_xor(q, 16); q += __shfl_xor(q, 32);
    if (quad == 0) {
      atomicAdd(&s1acc[nt * 16 + lr], s);
      atomicAdd(&q1acc[nt * 16 + lr], q);
    }
  }
  __syncthreads();
  if (tid < 64) {
    atomicAdd(&sums1[b * 128 + tid], s1acc[tid]);
    atomicAdd(&sums1[b * 128 + 64 + tid], q1acc[tid]);
  }
}

// ============ MFMA conv2 common (bf16 y1; a/d from LDS) =======================
struct Conv2Frag {
  bf16x8 bfr[8][2];   // [ntile][kstep]
  float  b2v[8];
};

__device__ __forceinline__ void load_w2_frags(const unsigned short* __restrict__ w2b,
                                              const float* __restrict__ b2,
                                              int lane, Conv2Frag& F) {
  const int quad = lane >> 4, lr = lane & 15;
  #pragma unroll
  for (int nt = 0; nt < 8; ++nt) {
    #pragma unroll
    for (int t = 0; t < 2; ++t)
      F.bfr[nt][t] = *(const bf16x8*)(w2b + (size_t)(nt * 16 + lr) * 64 + t * 32 + quad * 8);
    F.b2v[nt] = b2[nt * 16 + lr];
  }
}

__device__ __forceinline__ void conv2_wave_mfma(const float* __restrict__ y1,
                                                const float* a1s,   // LDS [64]
                                                const float* d1s,   // LDS [64]
                                                unsigned short* __restrict__ hrow, // [32][72]
                                                int wid, int lane,
                                                const Conv2Frag& F,
                                                f32x4 acc[2][8]) {
  const int quad = lane >> 4, lr = lane & 15;
  const int r = lane >> 1, c0 = (lane & 1) * 32;
  const unsigned short* yrow16 =
      (const unsigned short*)(y1 + (size_t)wid * 1024) + r * 64 + c0;
  const float4* ap = (const float4*)(a1s + c0);
  const float4* dp = (const float4*)(d1s + c0);
  #pragma unroll
  for (int gg = 0; gg < 4; ++gg) {
    bf16x8 yv = *(const bf16x8*)(yrow16 + gg * 8);
    float4 av0 = ap[gg * 2],     dv0 = dp[gg * 2];
    float4 av1 = ap[gg * 2 + 1], dv1 = dp[gg * 2 + 1];
    ushort4 s0, s1;
    s0.x = f2bf(fmaxf(0.0f, fmaf(bf2f((unsigned short)yv[0]), av0.x, dv0.x)));
    s0.y = f2bf(fmaxf(0.0f, fmaf(bf2f((unsigned short)yv[1]), av0.y, dv0.y)));
    s0.z = f2bf(fmaxf(0.0f, fmaf(bf2f((unsigned short)yv[2]), av0.z, dv0.z)));
    s0.w = f2bf(fmaxf(0.0f, fmaf(bf2f((unsigned short)yv[3]), av0.w, dv0.w)));
    s1.x = f2bf(fmaxf(0.0f, fmaf(bf2f((unsigned short)yv[4]), av1.x, dv1.x)));
    s1.y = f2bf(fmaxf(0.0f, fmaf(bf2f((unsigned short)yv[5]), av1.y, dv1.y)));
    s1.z = f2bf(fmaxf(0.0f, fmaf(bf2f((unsigned short)yv[6]), av1.z, dv1.z)));
    s1.w = f2bf(fmaxf(0.0f, fmaf(bf2f((unsigned short)yv[7]), av1.w, dv1.w)));
    *(ushort4*)(hrow + r * 72 + c0 + 8 * gg)     = s0;
    *(ushort4*)(hrow + r * 72 + c0 + 8 * gg + 4) = s1;
  }
  __builtin_amdgcn_s_waitcnt(0);            // drain lds writes (same wave consumes)
  __builtin_amdgcn_wave_barrier();
  #pragma unroll
  for (int mt = 0; mt < 2; ++mt)
    #pragma unroll
    for (int nt = 0; nt < 8; ++nt)
      acc[mt][nt] = (f32x4){0.f, 0.f, 0.f, 0.f};
  #pragma unroll
  for (int t = 0; t < 2; ++t) {
    bf16x8 a0 = *(const bf16x8*)(hrow + (0 + lr) * 72 + t * 32 + quad * 8);
    bf16x8 a1f = *(const bf16x8*)(hrow + (16 + lr) * 72 + t * 32 + quad * 8);
    #pragma unroll
    for (int nt = 0; nt < 8; ++nt) {
      acc[0][nt] = __builtin_amdgcn_mfma_f32_16x16x32_bf16(a0,  F.bfr[nt][t], acc[0][nt], 0, 0, 0);
      acc[1][nt] = __builtin_amdgcn_mfma_f32_16x16x32_bf16(a1f, F.bfr[nt][t], acc[1][nt], 0, 0, 0);
    }
  }
}

// ---------------- K5: conv2 (MFMA) -> GN2 stats + zmax/zmin (coeffs1 folded) --
// R7: computes a1/d1 per block from sums1 (deterministic, same add order as
// the old coeffs kernel) — removes the coeffs1 launch. Stats + zmax/zmin as
// in R4 (final = relu(a*zmax+d) / relu(a*zmin+d), bitwise identical).
__global__ __launch_bounds__(256) void conv2_stats_kernel(float* __restrict__ y1,
                                                          const float* __restrict__ sums1,
                                                          const float* __restrict__ g1w,
                                                          const float* __restrict__ g1b,
                                                          const unsigned short* __restrict__ w2b,
                                                          const float* __restrict__ b2,
                                                          float* __restrict__ sums2) {
  __shared__ __align__(16) unsigned short hsm[4][32 * 72];
  __shared__ float sacc[128], qacc[128];
  __shared__ float a1s[64], d1s[64];
  const int tid = threadIdx.x, lane = tid & 63, w = tid >> 6;
  const int wid = blockIdx.x * 4 + w;
  const int b = blockIdx.x >> 8;
  if (tid < 128) { sacc[tid] = 0.0f; qacc[tid] = 0.0f; }
  if (tid < 64) {   // coeffs1 for this b (cpg=2, invn=1/65536)
    int c = tid, g = c >> 1;
    float S = sums1[b * 128 + g * 2] + sums1[b * 128 + g * 2 + 1];
    float Q = sums1[b * 128 + 64 + g * 2] + sums1[b * 128 + 64 + g * 2 + 1];
    float mu = S * (1.0f / 65536.0f);
    float var = Q * (1.0f / 65536.0f) - mu * mu;
    float rs = 1.0f / sqrtf(var + 1e-5f);
    float ga = g1w[c];
    a1s[c] = rs * ga;
    d1s[c] = g1b[c] - mu * rs * ga;
  }
  __syncthreads();
  Conv2Frag F;
  load_w2_frags(w2b, b2, lane, F);
  f32x4 acc[2][8];
  conv2_wave_mfma(y1, a1s, d1s, hsm[w], wid, lane, F, acc);
  const int lr = lane & 15;
  float zmx[8], zmn[8];
  #pragma unroll
  for (int nt = 0; nt < 8; ++nt) {
    float s = 0, q = 0, mx = -3e38f, mn = 3e38f;
    #pragma unroll
    for (int mt = 0; mt < 2; ++mt)
      #pragma unroll
      for (int rg = 0; rg < 4; ++rg) {
        float z = acc[mt][nt][rg] + F.b2v[nt];
        s += z; q = fmaf(z, z, q);
        mx = fmaxf(mx, z); mn = fminf(mn, z);
      }
    atomicAdd(&sacc[nt * 16 + lr], s);
    atomicAdd(&qacc[nt * 16 + lr], q);
    mx = fmaxf(mx, __shfl_xor(mx, 16)); mx = fmaxf(mx, __shfl_xor(mx, 32));
    mn = fminf(mn, __shfl_xor(mn, 16)); mn = fminf(mn, __shfl_xor(mn, 32));
    zmx[nt] = mx; zmn[nt] = mn;
  }
  // store zmax/zmin (f32) into own consumed y1 tile head: [0..127]=max, [128..255]=min
  if (lane < 16) {
    float* zp = y1 + (size_t)wid * 1024;
    #pragma unroll
    for (int nt = 0; nt < 8; ++nt) {
      zp[nt * 16 + lr] = zmx[nt];
      zp[128 + nt * 16 + lr] = zmn[nt];
    }
  }
  __syncthreads();
  if (tid < 128) {
    atomicAdd(&sums2[b * 256 + tid], sacc[tid]);
    atomicAdd(&sums2[b * 256 + 128 + tid], qacc[tid]);
  }
}

// ---------------- K7: final-lite — coeffs2 folded + GN2 affine on zmax/zmin ---
__global__ __launch_bounds__(256) void final_lite(const float* __restrict__ y1,
                                                  const float* __restrict__ sums2,
                                                  const float* __restrict__ g2w,
                                                  const float* __restrict__ g2b,
                                                  float* __restrict__ nf) {
  __shared__ float a2s[128], d2s[128];
  const int tid = threadIdx.x;
  const int wid0 = blockIdx.x * 2;            // 8192 blocks x 2 wids (same b)
  const int b = wid0 >> 10;
  if (tid < 128) {   // coeffs2 for this b (cpg=4, invn=1/131072)
    int c = tid, g = c >> 2;
    float S = ((sums2[b * 256 + g * 4] + sums2[b * 256 + g * 4 + 1])
               + sums2[b * 256 + g * 4 + 2]) + sums2[b * 256 + g * 4 + 3];
    float Q = ((sums2[b * 256 + 128 + g * 4] + sums2[b * 256 + 128 + g * 4 + 1])
               + sums2[b * 256 + 128 + g * 4 + 2]) + sums2[b * 256 + 128 + g * 4 + 3];
    float mu = S * (1.0f / 131072.0f);
    float var = Q * (1.0f / 131072.0f) - mu * mu;
    float rs = 1.0f / sqrtf(var + 1e-5f);
    float ga = g2w[c];
    a2s[c] = rs * ga;
    d2s[c] = g2b[c] - mu * rs * ga;
  }
  __syncthreads();
  int wid = wid0 + (tid >> 7), c = tid & 127;
  const float* zp = y1 + (size_t)wid * 1024;
  float zmx = zp[c];
  float zmn = zp[128 + c];
  float az = a2s[c], dz = d2s[c];
  float z = (az >= 0.0f) ? zmx : zmn;
  nf[(size_t)wid * 128 + c] = fmaxf(0.0f, fmaf(z, az, dz));
}

extern "C" void kernel_launch(void* const* d_in, const int* in_sizes, int n_in,
                              void* d_out, int out_size, void* d_ws, size_t ws_size,
                              hipStream_t stream) {
  const float* xyz  = (const float*)d_in[0];
  const float* feat = (const float*)d_in[1];
  const float* w1   = (const float*)d_in[2];
  const float* b1   = (const float*)d_in[3];
  const float* g1w  = (const float*)d_in[4];
  const float* g1b  = (const float*)d_in[5];
  const float* w2   = (const float*)d_in[6];
  const float* b2   = (const float*)d_in[7];
  const float* g2w  = (const float*)d_in[8];
  const float* g2b  = (const float*)d_in[9];
  float* ws = (float*)d_ws;
  float* cent = (float*)d_out;                    // (B,M,3)
  float* nf   = (float*)d_out + BB * MM * 3;      // (B,M,128)
  const float4* pts4 = (const float4*)(ws + PTS4_OFF);
  int*   knn   = (int*)(ws + KNN_OFF);
  float* sums1 = ws + SUM1_OFF;
  float* sums2 = ws + SUM2_OFF;
  const unsigned short* w2b = (const unsigned short*)(ws + W2B_OFF);
  const unsigned short* w1b = (const unsigned short*)(ws + W1B_OFF);
  const unsigned short* feat16 = (const unsigned short*)(ws + FEAT16_OFF);
  float* y1 = ws + Y1_OFF;

  hipLaunchKernelGGL(k0_init, dim3(16384), dim3(256), 0, stream, xyz, feat, w1, w2, ws);
  hipLaunchKernelGGL(fps_kernel, dim3(16), dim3(256), 0, stream, xyz, cent);
  hipLaunchKernelGGL(knn_kernel, dim3(256), dim3(512), 0, stream, pts4, cent, knn);
  hipLaunchKernelGGL(conv1_kernel, dim3(4096), dim3(256), 0, stream,
                     xyz, feat16, cent, knn, w1b, b1, y1, sums1);
  hipLaunchKernelGGL(conv2_stats_kernel, dim3(4096), dim3(256), 0, stream,
                     y1, sums1, g1w, g1b, w2b, b2, sums2);
  hipLaunchKernelGGL(final_lite, dim3(8192), dim3(256), 0, stream,
                     y1, sums2, g2w, g2b, nf);
}

// Round 9
// 1446.720 us; speedup vs baseline: 1.1001x; 1.1001x over previous
//
#include <hip/hip_runtime.h>
#include <cstdint>

#define BB 16
#define NN 8192
#define MM 1024
#define KNN 32
#define CIN 64
#define HID 64
#define OCH 128

// workspace float offsets
#define KNN_OFF   0u          // 524288 ints
#define SUM1_OFF  524288u     // 2048
#define SUM2_OFF  526336u     // 4096
#define W2B_OFF   536576u     // 4096 floats = 8192 bf16 (w2 pre-converted)
#define W1B_OFF   540672u     // 3072 floats = 6144 bf16 (w1 padded 67->96, bf16)
#define Y1_OFF    543744u     // y1 bf16: 16384 tiles x 1024 floats (2048 bf16)
#define PTS4_OFF  Y1_OFF      // 131072 float4 (dead once conv1 runs; knn before conv1)
#define FEAT16_OFF (Y1_OFF + 16777216u)  // feat bf16: 4194304 u32 (8M bf16)

typedef unsigned long long u64;
typedef float f32x4 __attribute__((ext_vector_type(4)));
typedef float f32x2 __attribute__((ext_vector_type(2)));
typedef short bf16x8 __attribute__((ext_vector_type(8)));

__device__ __forceinline__ unsigned short f2bf(float f) {
  union { float f; unsigned u; } v; v.f = f;
  unsigned r = v.u + 0x7FFFu + ((v.u >> 16) & 1u);   // RNE
  return (unsigned short)(r >> 16);
}

__device__ __forceinline__ float bf2f(unsigned short u) {
  return __uint_as_float((unsigned)u << 16);
}

// DPP u64 max-reduction across a wave; full max lands in lane 63.
__device__ __forceinline__ u64 wave_max_u64(u64 v) {
  #define DPP_RND(ctrl, rm)                                                     \
  {                                                                             \
    int lo_ = __builtin_amdgcn_update_dpp(0, (int)(unsigned)(v & 0xFFFFFFFFull),\
                                          ctrl, rm, 0xf, true);                 \
    int hi_ = __builtin_amdgcn_update_dpp(0, (int)(unsigned)(v >> 32),          \
                                          ctrl, rm, 0xf, true);                 \
    u64 o_ = ((u64)(unsigned)hi_ << 32) | (unsigned)lo_;                        \
    v = o_ > v ? o_ : v;                                                        \
  }
  DPP_RND(0x111, 0xf)  // row_shr:1
  DPP_RND(0x112, 0xf)  // row_shr:2
  DPP_RND(0x114, 0xf)  // row_shr:4
  DPP_RND(0x118, 0xf)  // row_shr:8
  DPP_RND(0x142, 0xa)  // row_bcast:15 -> rows 1,3
  DPP_RND(0x143, 0xc)  // row_bcast:31 -> rows 2,3
  #undef DPP_RND
  return v;
}

// ---------------- K1: FPS (blocks 0-15) + init filler (blocks 16-255) ---------
// R8: (a) fps reverted EXACTLY to the R5/R6-verified scalar form (835us floor;
// R7's deferred-argmax post-scan cost +100 inst/step — reverted). (b) k0's init
// work folded in as filler blocks: fps uses 16 CUs, init grid-strides on the
// other 240 (no data overlap: fps reads xyz/writes cent+LDS; init writes ws).
// 136KB static LDS -> 1 block/CU -> all 256 blocks co-resident; init finishes
// in ~15us on CUs fps never touches. Deletes k0's serial wall + 1 launch gap.
__global__ __launch_bounds__(256) void fps_init_kernel(const float* __restrict__ xyz,
                                                       const float* __restrict__ feat,
                                                       const float* __restrict__ w1,
                                                       const float* __restrict__ w2,
                                                       float* __restrict__ ws,
                                                       float* __restrict__ cent) {
  #pragma clang fp contract(off)
  __shared__ float4 sp4[NN];     // 128 KB
  __shared__ u64 slots[MM];      // 8 KB
  const int tid = threadIdx.x;

  if (blockIdx.x >= 16) {        // ---------- init filler path ----------
    const int t0 = (blockIdx.x - 16) * 256 + tid;
    const int stride = 240 * 256;
    for (int t = t0; t < 12288; t += stride) ws[SUM1_OFF + t] = 0.0f;
    for (int t = t0; t < 4096; t += stride) {   // w2 -> bf16 pairs
      unsigned lo = f2bf(w2[2 * t]);
      unsigned hi = f2bf(w2[2 * t + 1]);
      ((unsigned*)(ws + W2B_OFF))[t] = lo | (hi << 16);
    }
    for (int t = t0; t < 6144; t += stride) {   // w1 padded 67->96 bf16
      int n = t / 96, kk = t % 96;
      float val = 0.0f;
      if (kk < 3) val = w1[n * 67 + kk];
      else if (kk >= 4 && kk < 68) val = w1[n * 67 + kk - 1];
      ((unsigned short*)(ws + W1B_OFF))[t] = f2bf(val);
    }
    for (int t = t0; t < BB * NN; t += stride) {  // pts4 with |p|^2 in w
      float x = xyz[(size_t)t * 3], y = xyz[(size_t)t * 3 + 1], z = xyz[(size_t)t * 3 + 2];
      ((float4*)(ws + PTS4_OFF))[t] = make_float4(x, y, z, (x * x + y * y) + z * z);
    }
    for (int t = t0; t < 4194304; t += stride) {  // feat f32 -> bf16 pairs
      float2 fv = *(const float2*)(feat + 2 * (size_t)t);
      unsigned lo = f2bf(fv.x), hi = f2bf(fv.y);
      ((unsigned*)(ws + FEAT16_OFF))[t] = lo | (hi << 16);
    }
    return;
  }

  // ---------- fps path (R5/R6-verified, 4 waves, 1/SIMD) ----------
  const int b = blockIdx.x;
  const float* xp = xyz + (size_t)b * NN * 3;
  f32x2 px[16], py[16], pz[16];
  float dist0[16], dist1[16];
  #pragma unroll
  for (int i = 0; i < 16; ++i) {
    int n0 = tid + (2 * i) * 256, n1 = tid + (2 * i + 1) * 256;
    float x0 = xp[n0 * 3], y0 = xp[n0 * 3 + 1], z0 = xp[n0 * 3 + 2];
    float x1 = xp[n1 * 3], y1 = xp[n1 * 3 + 1], z1 = xp[n1 * 3 + 2];
    px[i] = (f32x2){x0, x1}; py[i] = (f32x2){y0, y1}; pz[i] = (f32x2){z0, z1};
    sp4[n0] = make_float4(x0, y0, z0, 0.0f);
    sp4[n1] = make_float4(x1, y1, z1, 0.0f);
    dist0[i] = 1e10f; dist1[i] = 1e10f;
  }
  for (int s = tid; s < MM; s += 256) slots[s] = 0ull;
  __syncthreads();
  int far = 0;
  for (int step = 0; step < MM; ++step) {
    float4 c4 = sp4[far];
    f32x2 cx = (f32x2){c4.x, c4.x}, cy = (f32x2){c4.y, c4.y}, cz = (f32x2){c4.z, c4.z};
    float best = -1.0f; int bi = 0;
    #pragma unroll
    for (int i = 0; i < 16; ++i) {
      f32x2 dx = px[i] - cx, dy = py[i] - cy, dz = pz[i] - cz;
      f32x2 d = (dx * dx + dy * dy) + dz * dz;   // np: left-assoc, no fma (per slot)
      float dm0 = fminf(dist0[i], d.x);
      float dm1 = fminf(dist1[i], d.y);
      dist0[i] = dm0; dist1[i] = dm1;
      if (dm0 > best) { best = dm0; bi = tid + (2 * i) * 256; }      // strict >: lowest n
      if (dm1 > best) { best = dm1; bi = tid + (2 * i + 1) * 256; }
    }
    u64 key = ((u64)__float_as_uint(best) << 32) | (unsigned)(8191 - bi);
    key = wave_max_u64(key);
    if ((tid & 63) == 63) atomicMax(&slots[step], key);   // max dist, tie -> lowest idx
    __syncthreads();
    far = 8191 - (int)(unsigned)(slots[step] & 0xFFFFFFFFull);
  }
  // post-loop: cent[0] = start point 0; cent[s] = winner of step s-1.
  float* co = cent + (size_t)b * MM * 3;
  for (int s = tid; s < MM; s += 256) {
    int fs = (s == 0) ? 0 : (8191 - (int)(unsigned)(slots[s - 1] & 0xFFFFFFFFull));
    float4 c = sp4[fs];
    co[s * 3 + 0] = c.x; co[s * 3 + 1] = c.y; co[s * 3 + 2] = c.z;
  }
}

// ---------------- K2: kNN — 8-way N-split, bank-free buffers, tree merge ------
__global__ __launch_bounds__(512) void knn_kernel(const float4* __restrict__ pts4,
                                                  const float* __restrict__ cent,
                                                  int* __restrict__ knnout) {
  #pragma clang fp contract(off)
  __shared__ __align__(16) char smem[65536];
  unsigned* blo = (unsigned*)smem;              // [16][512] cand idx (bank-free)
  unsigned* bhi = (unsigned*)(smem + 32768);    // [16][512] cand key-hi
  u64* marea = (u64*)smem;                      // 4 areas x [32][64]; aliases buffers
                                                // AFTER the post-scan barrier (R5 lesson)
  const int tid = threadIdx.x;
  const int lane = tid & 63;
  const int w = tid >> 6;          // wave id = N-octant
  const int b = blockIdx.x >> 4;
  const int m = ((blockIdx.x & 15) << 6) + lane;
  const float* cp = cent + ((size_t)b * MM + m) * 3;
  float cx = cp[0], cy = cp[1], cz = cp[2];
  float cn2 = (cx * cx + cy * cy) + cz * cz;
  u64 key[32];
  {
    u64 initk = ((u64)(__float_as_uint(3e38f) ^ 0x80000000u) << 32) | 0xFFFFFFFFull;
    #pragma unroll
    for (int j = 0; j < 32; ++j) key[j] = initk;
  }
  float kthf = 3e38f;

  auto insert = [&](u64 cand) {   // ascending sorted insert, static indexing only
    bool cprev = false; u64 kprev = 0;
    #pragma unroll
    for (int j = 0; j < 32; ++j) {
      bool cj = cand < key[j];
      u64 cur = key[j];
      u64 nv = cj ? cand : cur;
      key[j] = cprev ? kprev : nv;
      cprev = cj; kprev = cur;
    }
    unsigned hb = (unsigned)(key[31] >> 32);
    unsigned ob = (hb & 0x80000000u) ? (hb ^ 0x80000000u) : ~hb;
    kthf = __uint_as_float(ob);
  };

  int cnt = 0;
  auto flush = [&]() {
    int mc = cnt;
    #pragma unroll
    for (int off = 1; off < 64; off <<= 1) { int o = __shfl_xor(mc, off); mc = o > mc ? o : mc; }
    for (int i = 0; i < mc; ++i) {
      u64 cand = ((u64)bhi[i * 512 + tid] << 32) | blo[i * 512 + tid];
      if (i < cnt && cand < key[31]) insert(cand);   // exact (d2,idx) lex decision
    }
    cnt = 0;
  };

  const int nbase = __builtin_amdgcn_readfirstlane(w * 1024);  // force SGPR -> s_load path
  const float4* pb = pts4 + (size_t)b * NN + nbase;
  for (int n0 = 0; n0 < 1024; n0 += 8) {
    #pragma unroll
    for (int j = 0; j < 8; ++j) {
      int n = n0 + j;
      float4 p = pb[n];
      float dot = fmaf(cz, p.z, fmaf(cy, p.y, cx * p.x));  // verified np-exact form
      float d2 = (cn2 + p.w) - 2.0f * dot;                  // separate ufunc ops
      if (d2 <= kthf) {                                     // exact re-check at insert
        unsigned db = __float_as_uint(d2);
        unsigned fk = db ^ (((int)db < 0) ? 0xFFFFFFFFu : 0x80000000u);
        blo[cnt * 512 + tid] = (unsigned)(nbase + n);
        bhi[cnt * 512 + tid] = fk;
        cnt++;
      }
    }
    if (__ballot(cnt >= 9)) flush();   // cap 16: <=8 carried + <=8 new
  }
  flush();
  __syncthreads();   // all waves done scanning; buffers dead -> marea aliasing safe

  auto publish = [&](int a) {
    u64* ap = marea + a * 2048;
    #pragma unroll
    for (int j = 0; j < 32; ++j) ap[j * 64 + lane] = key[j];   // [j][lane]: bank-free
  };
  auto merge_from = [&](int a) {
    u64* ap = marea + a * 2048;
    for (int j = 0; j < 32; ++j) {
      u64 cand = ap[j * 64 + lane];
      if (cand < key[31]) insert(cand);    // exact pairwise min-32 merge
    }
  };
  // tree merge 8->4->2->1 (all barriers at top level)
  if (w & 1) publish(w >> 1);
  __syncthreads();
  if (!(w & 1)) merge_from(w >> 1);
  __syncthreads();
  if (w == 2) publish(0);
  if (w == 6) publish(1);
  __syncthreads();
  if (w == 0) merge_from(0);
  if (w == 4) merge_from(1);
  __syncthreads();
  if (w == 4) publish(0);
  __syncthreads();
  if (w == 0) {
    merge_from(0);
    int* op = knnout + ((size_t)b * MM + m) * KNN;
    #pragma unroll
    for (int j = 0; j < 32; ++j) op[j] = (int)(key[j] & 0xFFFFFFFFull);
  }
}

// ---------------- K3: conv1 via MFMA + fused GN1 stats, bf16 y1/feat ----------
// A-frag: A[m=lane&15][k=quad*8+j] from LDS gf[32][104] bf16
// B-frag: B[k][n=lane&15] = w1b[n][k] (padded K layout; zeros kill pad lanes)
// D:      D[m=quad*4+reg][n=lane&15]  (verified m89/m91 mapping, same as conv2)
__global__ __launch_bounds__(256) void conv1_kernel(const float* __restrict__ xyz,
                                                    const unsigned short* __restrict__ feat16,
                                                    const float* __restrict__ cent,
                                                    const int* __restrict__ knn,
                                                    const unsigned short* __restrict__ w1b,
                                                    const float* __restrict__ b1,
                                                    float* __restrict__ y1,
                                                    float* __restrict__ sums1) {
  __shared__ __align__(16) unsigned short gsm[4][32 * 104];
  __shared__ float s1acc[64], q1acc[64];
  const int tid = threadIdx.x, lane = tid & 63, w = tid >> 6;
  const int wid = blockIdx.x * 4 + w;           // (b,m) pair 0..16383
  const int b = wid >> 10;
  unsigned short* gf = gsm[w];

  if (tid < 64) { s1acc[tid] = 0.0f; q1acc[tid] = 0.0f; }
  __syncthreads();

  int idxv = 0;
  if (lane < 32) idxv = knn[(size_t)wid * 32 + lane];

  // zero K-pad [64..96) per row (feat phase below overwrites [64..67])
  {
    int row = lane >> 1, h = (lane & 1) * 16;
    ushort4 z4 = {0, 0, 0, 0};
    *(ushort4*)(gf + row * 104 + 64 + h + 0)  = z4;
    *(ushort4*)(gf + row * 104 + 64 + h + 4)  = z4;
    *(ushort4*)(gf + row * 104 + 64 + h + 8)  = z4;
    *(ushort4*)(gf + row * 104 + 64 + h + 12) = z4;
  }
  // delta rows (lanes 0..31): gf[r][0..2] = xyz[idx]-cent, gf[r][3] = dummy 0
  const float* cp = cent + (size_t)wid * 3;
  float ccx = cp[0], ccy = cp[1], ccz = cp[2];
  if (lane < 32) {
    const float* pp = xyz + ((size_t)b * NN + idxv) * 3;
    ushort4 dv;
    dv.x = f2bf(pp[0] - ccx); dv.y = f2bf(pp[1] - ccy); dv.z = f2bf(pp[2] - ccz);
    dv.w = 0;
    *(ushort4*)(gf + lane * 104) = dv;
  }
  // feat: 32 rows x 128B bf16, gathered as 16B units (4 iters/lane)
  const unsigned short* fb = feat16 + (size_t)b * NN * 64;
  #pragma unroll
  for (int i = 0; i < 4; ++i) {
    int v = i * 64 + lane;          // 0..255 units of 16B
    int row = v >> 3, part = v & 7;
    int ridx = __shfl(idxv, row);
    uint4 fv = *(const uint4*)(fb + (size_t)ridx * 64 + part * 8);
    *(uint2*)(gf + row * 104 + 4 + part * 8)     = make_uint2(fv.x, fv.y);
    *(uint2*)(gf + row * 104 + 4 + part * 8 + 4) = make_uint2(fv.z, fv.w);
  }
  __builtin_amdgcn_s_waitcnt(0);
  __builtin_amdgcn_wave_barrier();

  const int quad = lane >> 4, lr = lane & 15;
  bf16x8 bw[4][3];
  float b1v[4];
  #pragma unroll
  for (int nt = 0; nt < 4; ++nt) {
    #pragma unroll
    for (int ks = 0; ks < 3; ++ks)
      bw[nt][ks] = *(const bf16x8*)(w1b + (size_t)(nt * 16 + lr) * 96 + ks * 32 + quad * 8);
    b1v[nt] = b1[nt * 16 + lr];
  }
  f32x4 acc[2][4];
  #pragma unroll
  for (int mt = 0; mt < 2; ++mt)
    #pragma unroll
    for (int nt = 0; nt < 4; ++nt)
      acc[mt][nt] = (f32x4){0.f, 0.f, 0.f, 0.f};
  #pragma unroll
  for (int ks = 0; ks < 3; ++ks) {
    bf16x8 a0 = *(const bf16x8*)(gf + (0 + lr) * 104 + ks * 32 + quad * 8);
    bf16x8 a1 = *(const bf16x8*)(gf + (16 + lr) * 104 + ks * 32 + quad * 8);
    #pragma unroll
    for (int nt = 0; nt < 4; ++nt) {
      acc[0][nt] = __builtin_amdgcn_mfma_f32_16x16x32_bf16(a0, bw[nt][ks], acc[0][nt], 0, 0, 0);
      acc[1][nt] = __builtin_amdgcn_mfma_f32_16x16x32_bf16(a1, bw[nt][ks], acc[1][nt], 0, 0, 0);
    }
  }
  unsigned short* yo16 = (unsigned short*)(y1 + (size_t)wid * 1024);
  float s_nt[4] = {0.f, 0.f, 0.f, 0.f};
  float q_nt[4] = {0.f, 0.f, 0.f, 0.f};
  #pragma unroll
  for (int mt = 0; mt < 2; ++mt)
    #pragma unroll
    for (int rg = 0; rg < 4; ++rg) {
      int row = mt * 16 + quad * 4 + rg;
      #pragma unroll
      for (int nt = 0; nt < 4; ++nt) {
        float z = acc[mt][nt][rg] + b1v[nt];
        yo16[row * 64 + nt * 16 + lr] = f2bf(z);
        s_nt[nt] += z;
        q_nt[nt] = fmaf(z, z, q_nt[nt]);
      }
    }
  // quad reduce (lanes lr, lr+16, lr+32, lr+48 hold the 4 row-quarters of ch c)
  #pragma unroll
  for (int nt = 0; nt < 4; ++nt) {
    float s = s_nt[nt], q = q_nt[nt];
    s += __shfl_xor(s, 16); s += __shfl_xor(s, 32);
    q += __shfl_xor(q, 16); q += __shfl_xor(q, 32);
    if (quad == 0) {
      atomicAdd(&s1acc[nt * 16 + lr], s);
      atomicAdd(&q1acc[nt * 16 + lr], q);
    }
  }
  __syncthreads();
  if (tid < 64) {
    atomicAdd(&sums1[b * 128 + tid], s1acc[tid]);
    atomicAdd(&sums1[b * 128 + 64 + tid], q1acc[tid]);
  }
}

// ============ MFMA conv2 common (bf16 y1; a/d from LDS) =======================
struct Conv2Frag {
  bf16x8 bfr[8][2];   // [ntile][kstep]
  float  b2v[8];
};

__device__ __forceinline__ void load_w2_frags(const unsigned short* __restrict__ w2b,
                                              const float* __restrict__ b2,
                                              int lane, Conv2Frag& F) {
  const int quad = lane >> 4, lr = lane & 15;
  #pragma unroll
  for (int nt = 0; nt < 8; ++nt) {
    #pragma unroll
    for (int t = 0; t < 2; ++t)
      F.bfr[nt][t] = *(const bf16x8*)(w2b + (size_t)(nt * 16 + lr) * 64 + t * 32 + quad * 8);
    F.b2v[nt] = b2[nt * 16 + lr];
  }
}

__device__ __forceinline__ void conv2_wave_mfma(const float* __restrict__ y1,
                                                const float* a1s,   // LDS [64]
                                                const float* d1s,   // LDS [64]
                                                unsigned short* __restrict__ hrow, // [32][72]
                                                int wid, int lane,
                                                const Conv2Frag& F,
                                                f32x4 acc[2][8]) {
  const int quad = lane >> 4, lr = lane & 15;
  const int r = lane >> 1, c0 = (lane & 1) * 32;
  const unsigned short* yrow16 =
      (const unsigned short*)(y1 + (size_t)wid * 1024) + r * 64 + c0;
  const float4* ap = (const float4*)(a1s + c0);
  const float4* dp = (const float4*)(d1s + c0);
  #pragma unroll
  for (int gg = 0; gg < 4; ++gg) {
    bf16x8 yv = *(const bf16x8*)(yrow16 + gg * 8);
    float4 av0 = ap[gg * 2],     dv0 = dp[gg * 2];
    float4 av1 = ap[gg * 2 + 1], dv1 = dp[gg * 2 + 1];
    ushort4 s0, s1;
    s0.x = f2bf(fmaxf(0.0f, fmaf(bf2f((unsigned short)yv[0]), av0.x, dv0.x)));
    s0.y = f2bf(fmaxf(0.0f, fmaf(bf2f((unsigned short)yv[1]), av0.y, dv0.y)));
    s0.z = f2bf(fmaxf(0.0f, fmaf(bf2f((unsigned short)yv[2]), av0.z, dv0.z)));
    s0.w = f2bf(fmaxf(0.0f, fmaf(bf2f((unsigned short)yv[3]), av0.w, dv0.w)));
    s1.x = f2bf(fmaxf(0.0f, fmaf(bf2f((unsigned short)yv[4]), av1.x, dv1.x)));
    s1.y = f2bf(fmaxf(0.0f, fmaf(bf2f((unsigned short)yv[5]), av1.y, dv1.y)));
    s1.z = f2bf(fmaxf(0.0f, fmaf(bf2f((unsigned short)yv[6]), av1.z, dv1.z)));
    s1.w = f2bf(fmaxf(0.0f, fmaf(bf2f((unsigned short)yv[7]), av1.w, dv1.w)));
    *(ushort4*)(hrow + r * 72 + c0 + 8 * gg)     = s0;
    *(ushort4*)(hrow + r * 72 + c0 + 8 * gg + 4) = s1;
  }
  __builtin_amdgcn_s_waitcnt(0);            // drain lds writes (same wave consumes)
  __builtin_amdgcn_wave_barrier();
  #pragma unroll
  for (int mt = 0; mt < 2; ++mt)
    #pragma unroll
    for (int nt = 0; nt < 8; ++nt)
      acc[mt][nt] = (f32x4){0.f, 0.f, 0.f, 0.f};
  #pragma unroll
  for (int t = 0; t < 2; ++t) {
    bf16x8 a0 = *(const bf16x8*)(hrow + (0 + lr) * 72 + t * 32 + quad * 8);
    bf16x8 a1f = *(const bf16x8*)(hrow + (16 + lr) * 72 + t * 32 + quad * 8);
    #pragma unroll
    for (int nt = 0; nt < 8; ++nt) {
      acc[0][nt] = __builtin_amdgcn_mfma_f32_16x16x32_bf16(a0,  F.bfr[nt][t], acc[0][nt], 0, 0, 0);
      acc[1][nt] = __builtin_amdgcn_mfma_f32_16x16x32_bf16(a1f, F.bfr[nt][t], acc[1][nt], 0, 0, 0);
    }
  }
}

// ---------------- K5: conv2 (MFMA) -> GN2 stats + zmax/zmin (coeffs1 folded) --
__global__ __launch_bounds__(256) void conv2_stats_kernel(float* __restrict__ y1,
                                                          const float* __restrict__ sums1,
                                                          const float* __restrict__ g1w,
                                                          const float* __restrict__ g1b,
                                                          const unsigned short* __restrict__ w2b,
                                                          const float* __restrict__ b2,
                                                          float* __restrict__ sums2) {
  __shared__ __align__(16) unsigned short hsm[4][32 * 72];
  __shared__ float sacc[128], qacc[128];
  __shared__ float a1s[64], d1s[64];
  const int tid = threadIdx.x, lane = tid & 63, w = tid >> 6;
  const int wid = blockIdx.x * 4 + w;
  const int b = blockIdx.x >> 8;
  if (tid < 128) { sacc[tid] = 0.0f; qacc[tid] = 0.0f; }
  if (tid < 64) {   // coeffs1 for this b (cpg=2, invn=1/65536)
    int c = tid, g = c >> 1;
    float S = sums1[b * 128 + g * 2] + sums1[b * 128 + g * 2 + 1];
    float Q = sums1[b * 128 + 64 + g * 2] + sums1[b * 128 + 64 + g * 2 + 1];
    float mu = S * (1.0f / 65536.0f);
    float var = Q * (1.0f / 65536.0f) - mu * mu;
    float rs = 1.0f / sqrtf(var + 1e-5f);
    float ga = g1w[c];
    a1s[c] = rs * ga;
    d1s[c] = g1b[c] - mu * rs * ga;
  }
  __syncthreads();
  Conv2Frag F;
  load_w2_frags(w2b, b2, lane, F);
  f32x4 acc[2][8];
  conv2_wave_mfma(y1, a1s, d1s, hsm[w], wid, lane, F, acc);
  const int lr = lane & 15;
  float zmx[8], zmn[8];
  #pragma unroll
  for (int nt = 0; nt < 8; ++nt) {
    float s = 0, q = 0, mx = -3e38f, mn = 3e38f;
    #pragma unroll
    for (int mt = 0; mt < 2; ++mt)
      #pragma unroll
      for (int rg = 0; rg < 4; ++rg) {
        float z = acc[mt][nt][rg] + F.b2v[nt];
        s += z; q = fmaf(z, z, q);
        mx = fmaxf(mx, z); mn = fminf(mn, z);
      }
    atomicAdd(&sacc[nt * 16 + lr], s);
    atomicAdd(&qacc[nt * 16 + lr], q);
    mx = fmaxf(mx, __shfl_xor(mx, 16)); mx = fmaxf(mx, __shfl_xor(mx, 32));
    mn = fminf(mn, __shfl_xor(mn, 16)); mn = fminf(mn, __shfl_xor(mn, 32));
    zmx[nt] = mx; zmn[nt] = mn;
  }
  // store zmax/zmin (f32) into own consumed y1 tile head: [0..127]=max, [128..255]=min
  if (lane < 16) {
    float* zp = y1 + (size_t)wid * 1024;
    #pragma unroll
    for (int nt = 0; nt < 8; ++nt) {
      zp[nt * 16 + lr] = zmx[nt];
      zp[128 + nt * 16 + lr] = zmn[nt];
    }
  }
  __syncthreads();
  if (tid < 128) {
    atomicAdd(&sums2[b * 256 + tid], sacc[tid]);
    atomicAdd(&sums2[b * 256 + 128 + tid], qacc[tid]);
  }
}

// ---------------- K7: final-lite — coeffs2 folded + GN2 affine on zmax/zmin ---
__global__ __launch_bounds__(256) void final_lite(const float* __restrict__ y1,
                                                  const float* __restrict__ sums2,
                                                  const float* __restrict__ g2w,
                                                  const float* __restrict__ g2b,
                                                  float* __restrict__ nf) {
  __shared__ float a2s[128], d2s[128];
  const int tid = threadIdx.x;
  const int wid0 = blockIdx.x * 2;            // 8192 blocks x 2 wids (same b)
  const int b = wid0 >> 10;
  if (tid < 128) {   // coeffs2 for this b (cpg=4, invn=1/131072)
    int c = tid, g = c >> 2;
    float S = ((sums2[b * 256 + g * 4] + sums2[b * 256 + g * 4 + 1])
               + sums2[b * 256 + g * 4 + 2]) + sums2[b * 256 + g * 4 + 3];
    float Q = ((sums2[b * 256 + 128 + g * 4] + sums2[b * 256 + 128 + g * 4 + 1])
               + sums2[b * 256 + 128 + g * 4 + 2]) + sums2[b * 256 + 128 + g * 4 + 3];
    float mu = S * (1.0f / 131072.0f);
    float var = Q * (1.0f / 131072.0f) - mu * mu;
    float rs = 1.0f / sqrtf(var + 1e-5f);
    float ga = g2w[c];
    a2s[c] = rs * ga;
    d2s[c] = g2b[c] - mu * rs * ga;
  }
  __syncthreads();
  int wid = wid0 + (tid >> 7), c = tid & 127;
  const float* zp = y1 + (size_t)wid * 1024;
  float zmx = zp[c];
  float zmn = zp[128 + c];
  float az = a2s[c], dz = d2s[c];
  float z = (az >= 0.0f) ? zmx : zmn;
  nf[(size_t)wid * 128 + c] = fmaxf(0.0f, fmaf(z, az, dz));
}

extern "C" void kernel_launch(void* const* d_in, const int* in_sizes, int n_in,
                              void* d_out, int out_size, void* d_ws, size_t ws_size,
                              hipStream_t stream) {
  const float* xyz  = (const float*)d_in[0];
  const float* feat = (const float*)d_in[1];
  const float* w1   = (const float*)d_in[2];
  const float* b1   = (const float*)d_in[3];
  const float* g1w  = (const float*)d_in[4];
  const float* g1b  = (const float*)d_in[5];
  const float* w2   = (const float*)d_in[6];
  const float* b2   = (const float*)d_in[7];
  const float* g2w  = (const float*)d_in[8];
  const float* g2b  = (const float*)d_in[9];
  float* ws = (float*)d_ws;
  float* cent = (float*)d_out;                    // (B,M,3)
  float* nf   = (float*)d_out + BB * MM * 3;      // (B,M,128)
  const float4* pts4 = (const float4*)(ws + PTS4_OFF);
  int*   knn   = (int*)(ws + KNN_OFF);
  float* sums1 = ws + SUM1_OFF;
  float* sums2 = ws + SUM2_OFF;
  const unsigned short* w2b = (const unsigned short*)(ws + W2B_OFF);
  const unsigned short* w1b = (const unsigned short*)(ws + W1B_OFF);
  const unsigned short* feat16 = (const unsigned short*)(ws + FEAT16_OFF);
  float* y1 = ws + Y1_OFF;

  hipLaunchKernelGGL(fps_init_kernel, dim3(256), dim3(256), 0, stream,
                     xyz, feat, w1, w2, ws, cent);
  hipLaunchKernelGGL(knn_kernel, dim3(256), dim3(512), 0, stream, pts4, cent, knn);
  hipLaunchKernelGGL(conv1_kernel, dim3(4096), dim3(256), 0, stream,
                     xyz, feat16, cent, knn, w1b, b1, y1, sums1);
  hipLaunchKernelGGL(conv2_stats_kernel, dim3(4096), dim3(256), 0, stream,
                     y1, sums1, g1w, g1b, w2b, b2, sums2);
  hipLaunchKernelGGL(final_lite, dim3(8192), dim3(256), 0, stream,
                     y1, sums2, g2w, g2b, nf);
}

// Round 10
// 1439.312 us; speedup vs baseline: 1.1058x; 1.0051x over previous
//
#include <hip/hip_runtime.h>
#include <cstdint>

#define BB 16
#define NN 8192
#define MM 1024
#define KNN 32
#define CIN 64
#define HID 64
#define OCH 128

// workspace float offsets
#define KNN_OFF   0u          // 524288 ints
#define SUM1_OFF  524288u     // 2048
#define SUM2_OFF  526336u     // 4096
#define W2B_OFF   536576u     // 4096 floats = 8192 bf16 (w2 pre-converted)
#define W1B_OFF   540672u     // 3072 floats = 6144 bf16 (w1 padded 67->96, bf16)
#define Y1_OFF    543744u     // y1 bf16: 16384 tiles x 1024 floats (2048 bf16)
#define PTS4_OFF  Y1_OFF      // 131072 float4 (dead once conv1 runs; knn before conv1)
#define FEAT16_OFF (Y1_OFF + 16777216u)  // feat bf16: 4194304 u32 (8M bf16)

typedef unsigned long long u64;
typedef float f32x4 __attribute__((ext_vector_type(4)));
typedef float f32x2 __attribute__((ext_vector_type(2)));
typedef short bf16x8 __attribute__((ext_vector_type(8)));

__device__ __forceinline__ unsigned short f2bf(float f) {
  union { float f; unsigned u; } v; v.f = f;
  unsigned r = v.u + 0x7FFFu + ((v.u >> 16) & 1u);   // RNE
  return (unsigned short)(r >> 16);
}

__device__ __forceinline__ float bf2f(unsigned short u) {
  return __uint_as_float((unsigned)u << 16);
}

// DPP u64 max-reduction across a wave; full max lands in lane 63.
__device__ __forceinline__ u64 wave_max_u64(u64 v) {
  #define DPP_RND(ctrl, rm)                                                     \
  {                                                                             \
    int lo_ = __builtin_amdgcn_update_dpp(0, (int)(unsigned)(v & 0xFFFFFFFFull),\
                                          ctrl, rm, 0xf, true);                 \
    int hi_ = __builtin_amdgcn_update_dpp(0, (int)(unsigned)(v >> 32),          \
                                          ctrl, rm, 0xf, true);                 \
    u64 o_ = ((u64)(unsigned)hi_ << 32) | (unsigned)lo_;                        \
    v = o_ > v ? o_ : v;                                                        \
  }
  DPP_RND(0x111, 0xf)  // row_shr:1
  DPP_RND(0x112, 0xf)  // row_shr:2
  DPP_RND(0x114, 0xf)  // row_shr:4
  DPP_RND(0x118, 0xf)  // row_shr:8
  DPP_RND(0x142, 0xa)  // row_bcast:15 -> rows 1,3
  DPP_RND(0x143, 0xc)  // row_bcast:31 -> rows 2,3
  #undef DPP_RND
  return v;
}

// ---------------- K1: FPS (blocks 0-15) + init filler (blocks 16-255) ---------
// R9: cross-wave combine de-atomized at the proven-optimal W=4: lane63 of each
// wave plain-stores its reduced key into wred[step&1][w] (parity double-buffer
// = WAR-safe across the single barrier, R1-verified protocol); after the
// barrier every thread merges the 4 keys locally (broadcast LDS reads + 3 u64
// max-selects). Removes the 4-way serialized LDS atomicMax + the dependent
// read of the just-updated slot (~150-400cy/step). tid0 archives the winner
// to slots[step] (fire-and-forget; next barrier drains it) for the replay.
// Selection semantics bit-identical: same keys, commutative max, no ties.
__global__ __launch_bounds__(256) void fps_init_kernel(const float* __restrict__ xyz,
                                                       const float* __restrict__ feat,
                                                       const float* __restrict__ w1,
                                                       const float* __restrict__ w2,
                                                       float* __restrict__ ws,
                                                       float* __restrict__ cent) {
  #pragma clang fp contract(off)
  __shared__ float4 sp4[NN];     // 128 KB
  __shared__ u64 slots[MM];      // 8 KB (replay archive; tid0 plain-stores)
  __shared__ u64 wred[2][4];     // [parity][wave]
  const int tid = threadIdx.x;

  if (blockIdx.x >= 16) {        // ---------- init filler path ----------
    const int t0 = (blockIdx.x - 16) * 256 + tid;
    const int stride = 240 * 256;
    for (int t = t0; t < 12288; t += stride) ws[SUM1_OFF + t] = 0.0f;
    for (int t = t0; t < 4096; t += stride) {   // w2 -> bf16 pairs
      unsigned lo = f2bf(w2[2 * t]);
      unsigned hi = f2bf(w2[2 * t + 1]);
      ((unsigned*)(ws + W2B_OFF))[t] = lo | (hi << 16);
    }
    for (int t = t0; t < 6144; t += stride) {   // w1 padded 67->96 bf16
      int n = t / 96, kk = t % 96;
      float val = 0.0f;
      if (kk < 3) val = w1[n * 67 + kk];
      else if (kk >= 4 && kk < 68) val = w1[n * 67 + kk - 1];
      ((unsigned short*)(ws + W1B_OFF))[t] = f2bf(val);
    }
    for (int t = t0; t < BB * NN; t += stride) {  // pts4 with |p|^2 in w
      float x = xyz[(size_t)t * 3], y = xyz[(size_t)t * 3 + 1], z = xyz[(size_t)t * 3 + 2];
      ((float4*)(ws + PTS4_OFF))[t] = make_float4(x, y, z, (x * x + y * y) + z * z);
    }
    for (int t = t0; t < 4194304; t += stride) {  // feat f32 -> bf16 pairs
      float2 fv = *(const float2*)(feat + 2 * (size_t)t);
      unsigned lo = f2bf(fv.x), hi = f2bf(fv.y);
      ((unsigned*)(ws + FEAT16_OFF))[t] = lo | (hi << 16);
    }
    return;
  }

  // ---------- fps path (4 waves, 1/SIMD; scalar R5-verified math) ----------
  const int b = blockIdx.x;
  const int w = tid >> 6;
  const float* xp = xyz + (size_t)b * NN * 3;
  f32x2 px[16], py[16], pz[16];
  float dist0[16], dist1[16];
  #pragma unroll
  for (int i = 0; i < 16; ++i) {
    int n0 = tid + (2 * i) * 256, n1 = tid + (2 * i + 1) * 256;
    float x0 = xp[n0 * 3], y0 = xp[n0 * 3 + 1], z0 = xp[n0 * 3 + 2];
    float x1 = xp[n1 * 3], y1 = xp[n1 * 3 + 1], z1 = xp[n1 * 3 + 2];
    px[i] = (f32x2){x0, x1}; py[i] = (f32x2){y0, y1}; pz[i] = (f32x2){z0, z1};
    sp4[n0] = make_float4(x0, y0, z0, 0.0f);
    sp4[n1] = make_float4(x1, y1, z1, 0.0f);
    dist0[i] = 1e10f; dist1[i] = 1e10f;
  }
  __syncthreads();
  int far = 0;
  for (int step = 0; step < MM; ++step) {
    float4 c4 = sp4[far];
    f32x2 cx = (f32x2){c4.x, c4.x}, cy = (f32x2){c4.y, c4.y}, cz = (f32x2){c4.z, c4.z};
    float best = -1.0f; int bi = 0;
    #pragma unroll
    for (int i = 0; i < 16; ++i) {
      f32x2 dx = px[i] - cx, dy = py[i] - cy, dz = pz[i] - cz;
      f32x2 d = (dx * dx + dy * dy) + dz * dz;   // np: left-assoc, no fma (per slot)
      float dm0 = fminf(dist0[i], d.x);
      float dm1 = fminf(dist1[i], d.y);
      dist0[i] = dm0; dist1[i] = dm1;
      if (dm0 > best) { best = dm0; bi = tid + (2 * i) * 256; }      // strict >: lowest n
      if (dm1 > best) { best = dm1; bi = tid + (2 * i + 1) * 256; }
    }
    u64 key = ((u64)__float_as_uint(best) << 32) | (unsigned)(8191 - bi);
    key = wave_max_u64(key);
    const int p = step & 1;
    if ((tid & 63) == 63) wred[p][w] = key;      // plain store, no atomic
    __syncthreads();
    u64 k0 = wred[p][0], k1 = wred[p][1], k2 = wred[p][2], k3 = wred[p][3];
    u64 m01 = k0 > k1 ? k0 : k1;
    u64 m23 = k2 > k3 ? k2 : k3;
    u64 bk = m01 > m23 ? m01 : m23;              // commutative max, tie-free keys
    if (tid == 0) slots[step] = bk;              // archive for replay (off-path)
    far = 8191 - (int)(unsigned)(bk & 0xFFFFFFFFull);
  }
  __syncthreads();   // make tid0's slots[] archive visible to all
  // replay: cent[0] = start point 0; cent[s] = winner of step s-1.
  float* co = cent + (size_t)b * MM * 3;
  for (int s = tid; s < MM; s += 256) {
    int fs = (s == 0) ? 0 : (8191 - (int)(unsigned)(slots[s - 1] & 0xFFFFFFFFull));
    float4 c = sp4[fs];
    co[s * 3 + 0] = c.x; co[s * 3 + 1] = c.y; co[s * 3 + 2] = c.z;
  }
}

// ---------------- K2: kNN — 8-way N-split, bank-free buffers, tree merge ------
__global__ __launch_bounds__(512) void knn_kernel(const float4* __restrict__ pts4,
                                                  const float* __restrict__ cent,
                                                  int* __restrict__ knnout) {
  #pragma clang fp contract(off)
  __shared__ __align__(16) char smem[65536];
  unsigned* blo = (unsigned*)smem;              // [16][512] cand idx (bank-free)
  unsigned* bhi = (unsigned*)(smem + 32768);    // [16][512] cand key-hi
  u64* marea = (u64*)smem;                      // 4 areas x [32][64]; aliases buffers
                                                // AFTER the post-scan barrier (R5 lesson)
  const int tid = threadIdx.x;
  const int lane = tid & 63;
  const int w = tid >> 6;          // wave id = N-octant
  const int b = blockIdx.x >> 4;
  const int m = ((blockIdx.x & 15) << 6) + lane;
  const float* cp = cent + ((size_t)b * MM + m) * 3;
  float cx = cp[0], cy = cp[1], cz = cp[2];
  float cn2 = (cx * cx + cy * cy) + cz * cz;
  u64 key[32];
  {
    u64 initk = ((u64)(__float_as_uint(3e38f) ^ 0x80000000u) << 32) | 0xFFFFFFFFull;
    #pragma unroll
    for (int j = 0; j < 32; ++j) key[j] = initk;
  }
  float kthf = 3e38f;

  auto insert = [&](u64 cand) {   // ascending sorted insert, static indexing only
    bool cprev = false; u64 kprev = 0;
    #pragma unroll
    for (int j = 0; j < 32; ++j) {
      bool cj = cand < key[j];
      u64 cur = key[j];
      u64 nv = cj ? cand : cur;
      key[j] = cprev ? kprev : nv;
      cprev = cj; kprev = cur;
    }
    unsigned hb = (unsigned)(key[31] >> 32);
    unsigned ob = (hb & 0x80000000u) ? (hb ^ 0x80000000u) : ~hb;
    kthf = __uint_as_float(ob);
  };

  int cnt = 0;
  auto flush = [&]() {
    int mc = cnt;
    #pragma unroll
    for (int off = 1; off < 64; off <<= 1) { int o = __shfl_xor(mc, off); mc = o > mc ? o : mc; }
    for (int i = 0; i < mc; ++i) {
      u64 cand = ((u64)bhi[i * 512 + tid] << 32) | blo[i * 512 + tid];
      if (i < cnt && cand < key[31]) insert(cand);   // exact (d2,idx) lex decision
    }
    cnt = 0;
  };

  const int nbase = __builtin_amdgcn_readfirstlane(w * 1024);  // force SGPR -> s_load path
  const float4* pb = pts4 + (size_t)b * NN + nbase;
  for (int n0 = 0; n0 < 1024; n0 += 8) {
    #pragma unroll
    for (int j = 0; j < 8; ++j) {
      int n = n0 + j;
      float4 p = pb[n];
      float dot = fmaf(cz, p.z, fmaf(cy, p.y, cx * p.x));  // verified np-exact form
      float d2 = (cn2 + p.w) - 2.0f * dot;                  // separate ufunc ops
      if (d2 <= kthf) {                                     // exact re-check at insert
        unsigned db = __float_as_uint(d2);
        unsigned fk = db ^ (((int)db < 0) ? 0xFFFFFFFFu : 0x80000000u);
        blo[cnt * 512 + tid] = (unsigned)(nbase + n);
        bhi[cnt * 512 + tid] = fk;
        cnt++;
      }
    }
    if (__ballot(cnt >= 9)) flush();   // cap 16: <=8 carried + <=8 new
  }
  flush();
  __syncthreads();   // all waves done scanning; buffers dead -> marea aliasing safe

  auto publish = [&](int a) {
    u64* ap = marea + a * 2048;
    #pragma unroll
    for (int j = 0; j < 32; ++j) ap[j * 64 + lane] = key[j];   // [j][lane]: bank-free
  };
  auto merge_from = [&](int a) {
    u64* ap = marea + a * 2048;
    for (int j = 0; j < 32; ++j) {
      u64 cand = ap[j * 64 + lane];
      if (cand < key[31]) insert(cand);    // exact pairwise min-32 merge
    }
  };
  // tree merge 8->4->2->1 (all barriers at top level)
  if (w & 1) publish(w >> 1);
  __syncthreads();
  if (!(w & 1)) merge_from(w >> 1);
  __syncthreads();
  if (w == 2) publish(0);
  if (w == 6) publish(1);
  __syncthreads();
  if (w == 0) merge_from(0);
  if (w == 4) merge_from(1);
  __syncthreads();
  if (w == 4) publish(0);
  __syncthreads();
  if (w == 0) {
    merge_from(0);
    int* op = knnout + ((size_t)b * MM + m) * KNN;
    #pragma unroll
    for (int j = 0; j < 32; ++j) op[j] = (int)(key[j] & 0xFFFFFFFFull);
  }
}

// ---------------- K3: conv1 via MFMA + fused GN1 stats, bf16 y1/feat ----------
// A-frag: A[m=lane&15][k=quad*8+j] from LDS gf[32][104] bf16
// B-frag: B[k][n=lane&15] = w1b[n][k] (padded K layout; zeros kill pad lanes)
// D:      D[m=quad*4+reg][n=lane&15]  (verified m89/m91 mapping, same as conv2)
__global__ __launch_bounds__(256) void conv1_kernel(const float* __restrict__ xyz,
                                                    const unsigned short* __restrict__ feat16,
                                                    const float* __restrict__ cent,
                                                    const int* __restrict__ knn,
                                                    const unsigned short* __restrict__ w1b,
                                                    const float* __restrict__ b1,
                                                    float* __restrict__ y1,
                                                    float* __restrict__ sums1) {
  __shared__ __align__(16) unsigned short gsm[4][32 * 104];
  __shared__ float s1acc[64], q1acc[64];
  const int tid = threadIdx.x, lane = tid & 63, w = tid >> 6;
  const int wid = blockIdx.x * 4 + w;           // (b,m) pair 0..16383
  const int b = wid >> 10;
  unsigned short* gf = gsm[w];

  if (tid < 64) { s1acc[tid] = 0.0f; q1acc[tid] = 0.0f; }
  __syncthreads();

  int idxv = 0;
  if (lane < 32) idxv = knn[(size_t)wid * 32 + lane];

  // zero K-pad [64..96) per row (feat phase below overwrites [64..67])
  {
    int row = lane >> 1, h = (lane & 1) * 16;
    ushort4 z4 = {0, 0, 0, 0};
    *(ushort4*)(gf + row * 104 + 64 + h + 0)  = z4;
    *(ushort4*)(gf + row * 104 + 64 + h + 4)  = z4;
    *(ushort4*)(gf + row * 104 + 64 + h + 8)  = z4;
    *(ushort4*)(gf + row * 104 + 64 + h + 12) = z4;
  }
  // delta rows (lanes 0..31): gf[r][0..2] = xyz[idx]-cent, gf[r][3] = dummy 0
  const float* cp = cent + (size_t)wid * 3;
  float ccx = cp[0], ccy = cp[1], ccz = cp[2];
  if (lane < 32) {
    const float* pp = xyz + ((size_t)b * NN + idxv) * 3;
    ushort4 dv;
    dv.x = f2bf(pp[0] - ccx); dv.y = f2bf(pp[1] - ccy); dv.z = f2bf(pp[2] - ccz);
    dv.w = 0;
    *(ushort4*)(gf + lane * 104) = dv;
  }
  // feat: 32 rows x 128B bf16, gathered as 16B units (4 iters/lane)
  const unsigned short* fb = feat16 + (size_t)b * NN * 64;
  #pragma unroll
  for (int i = 0; i < 4; ++i) {
    int v = i * 64 + lane;          // 0..255 units of 16B
    int row = v >> 3, part = v & 7;
    int ridx = __shfl(idxv, row);
    uint4 fv = *(const uint4*)(fb + (size_t)ridx * 64 + part * 8);
    *(uint2*)(gf + row * 104 + 4 + part * 8)     = make_uint2(fv.x, fv.y);
    *(uint2*)(gf + row * 104 + 4 + part * 8 + 4) = make_uint2(fv.z, fv.w);
  }
  __builtin_amdgcn_s_waitcnt(0);
  __builtin_amdgcn_wave_barrier();

  const int quad = lane >> 4, lr = lane & 15;
  bf16x8 bw[4][3];
  float b1v[4];
  #pragma unroll
  for (int nt = 0; nt < 4; ++nt) {
    #pragma unroll
    for (int ks = 0; ks < 3; ++ks)
      bw[nt][ks] = *(const bf16x8*)(w1b + (size_t)(nt * 16 + lr) * 96 + ks * 32 + quad * 8);
    b1v[nt] = b1[nt * 16 + lr];
  }
  f32x4 acc[2][4];
  #pragma unroll
  for (int mt = 0; mt < 2; ++mt)
    #pragma unroll
    for (int nt = 0; nt < 4; ++nt)
      acc[mt][nt] = (f32x4){0.f, 0.f, 0.f, 0.f};
  #pragma unroll
  for (int ks = 0; ks < 3; ++ks) {
    bf16x8 a0 = *(const bf16x8*)(gf + (0 + lr) * 104 + ks * 32 + quad * 8);
    bf16x8 a1 = *(const bf16x8*)(gf + (16 + lr) * 104 + ks * 32 + quad * 8);
    #pragma unroll
    for (int nt = 0; nt < 4; ++nt) {
      acc[0][nt] = __builtin_amdgcn_mfma_f32_16x16x32_bf16(a0, bw[nt][ks], acc[0][nt], 0, 0, 0);
      acc[1][nt] = __builtin_amdgcn_mfma_f32_16x16x32_bf16(a1, bw[nt][ks], acc[1][nt], 0, 0, 0);
    }
  }
  unsigned short* yo16 = (unsigned short*)(y1 + (size_t)wid * 1024);
  float s_nt[4] = {0.f, 0.f, 0.f, 0.f};
  float q_nt[4] = {0.f, 0.f, 0.f, 0.f};
  #pragma unroll
  for (int mt = 0; mt < 2; ++mt)
    #pragma unroll
    for (int rg = 0; rg < 4; ++rg) {
      int row = mt * 16 + quad * 4 + rg;
      #pragma unroll
      for (int nt = 0; nt < 4; ++nt) {
        float z = acc[mt][nt][rg] + b1v[nt];
        yo16[row * 64 + nt * 16 + lr] = f2bf(z);
        s_nt[nt] += z;
        q_nt[nt] = fmaf(z, z, q_nt[nt]);
      }
    }
  // quad reduce (lanes lr, lr+16, lr+32, lr+48 hold the 4 row-quarters of ch c)
  #pragma unroll
  for (int nt = 0; nt < 4; ++nt) {
    float s = s_nt[nt], q = q_nt[nt];
    s += __shfl_xor(s, 16); s += __shfl_xor(s, 32);
    q += __shfl_xor(q, 16); q += __shfl_xor(q, 32);
    if (quad == 0) {
      atomicAdd(&s1acc[nt * 16 + lr], s);
      atomicAdd(&q1acc[nt * 16 + lr], q);
    }
  }
  __syncthreads();
  if (tid < 64) {
    atomicAdd(&sums1[b * 128 + tid], s1acc[tid]);
    atomicAdd(&sums1[b * 128 + 64 + tid], q1acc[tid]);
  }
}

// ============ MFMA conv2 common (bf16 y1; a/d from LDS) =======================
struct Conv2Frag {
  bf16x8 bfr[8][2];   // [ntile][kstep]
  float  b2v[8];
};

__device__ __forceinline__ void load_w2_frags(const unsigned short* __restrict__ w2b,
                                              const float* __restrict__ b2,
                                              int lane, Conv2Frag& F) {
  const int quad = lane >> 4, lr = lane & 15;
  #pragma unroll
  for (int nt = 0; nt < 8; ++nt) {
    #pragma unroll
    for (int t = 0; t < 2; ++t)
      F.bfr[nt][t] = *(const bf16x8*)(w2b + (size_t)(nt * 16 + lr) * 64 + t * 32 + quad * 8);
    F.b2v[nt] = b2[nt * 16 + lr];
  }
}

__device__ __forceinline__ void conv2_wave_mfma(const float* __restrict__ y1,
                                                const float* a1s,   // LDS [64]
                                                const float* d1s,   // LDS [64]
                                                unsigned short* __restrict__ hrow, // [32][72]
                                                int wid, int lane,
                                                const Conv2Frag& F,
                                                f32x4 acc[2][8]) {
  const int quad = lane >> 4, lr = lane & 15;
  const int r = lane >> 1, c0 = (lane & 1) * 32;
  const unsigned short* yrow16 =
      (const unsigned short*)(y1 + (size_t)wid * 1024) + r * 64 + c0;
  const float4* ap = (const float4*)(a1s + c0);
  const float4* dp = (const float4*)(d1s + c0);
  #pragma unroll
  for (int gg = 0; gg < 4; ++gg) {
    bf16x8 yv = *(const bf16x8*)(yrow16 + gg * 8);
    float4 av0 = ap[gg * 2],     dv0 = dp[gg * 2];
    float4 av1 = ap[gg * 2 + 1], dv1 = dp[gg * 2 + 1];
    ushort4 s0, s1;
    s0.x = f2bf(fmaxf(0.0f, fmaf(bf2f((unsigned short)yv[0]), av0.x, dv0.x)));
    s0.y = f2bf(fmaxf(0.0f, fmaf(bf2f((unsigned short)yv[1]), av0.y, dv0.y)));
    s0.z = f2bf(fmaxf(0.0f, fmaf(bf2f((unsigned short)yv[2]), av0.z, dv0.z)));
    s0.w = f2bf(fmaxf(0.0f, fmaf(bf2f((unsigned short)yv[3]), av0.w, dv0.w)));
    s1.x = f2bf(fmaxf(0.0f, fmaf(bf2f((unsigned short)yv[4]), av1.x, dv1.x)));
    s1.y = f2bf(fmaxf(0.0f, fmaf(bf2f((unsigned short)yv[5]), av1.y, dv1.y)));
    s1.z = f2bf(fmaxf(0.0f, fmaf(bf2f((unsigned short)yv[6]), av1.z, dv1.z)));
    s1.w = f2bf(fmaxf(0.0f, fmaf(bf2f((unsigned short)yv[7]), av1.w, dv1.w)));
    *(ushort4*)(hrow + r * 72 + c0 + 8 * gg)     = s0;
    *(ushort4*)(hrow + r * 72 + c0 + 8 * gg + 4) = s1;
  }
  __builtin_amdgcn_s_waitcnt(0);            // drain lds writes (same wave consumes)
  __builtin_amdgcn_wave_barrier();
  #pragma unroll
  for (int mt = 0; mt < 2; ++mt)
    #pragma unroll
    for (int nt = 0; nt < 8; ++nt)
      acc[mt][nt] = (f32x4){0.f, 0.f, 0.f, 0.f};
  #pragma unroll
  for (int t = 0; t < 2; ++t) {
    bf16x8 a0 = *(const bf16x8*)(hrow + (0 + lr) * 72 + t * 32 + quad * 8);
    bf16x8 a1f = *(const bf16x8*)(hrow + (16 + lr) * 72 + t * 32 + quad * 8);
    #pragma unroll
    for (int nt = 0; nt < 8; ++nt) {
      acc[0][nt] = __builtin_amdgcn_mfma_f32_16x16x32_bf16(a0,  F.bfr[nt][t], acc[0][nt], 0, 0, 0);
      acc[1][nt] = __builtin_amdgcn_mfma_f32_16x16x32_bf16(a1f, F.bfr[nt][t], acc[1][nt], 0, 0, 0);
    }
  }
}

// ---------------- K5: conv2 (MFMA) -> GN2 stats + zmax/zmin (coeffs1 folded) --
__global__ __launch_bounds__(256) void conv2_stats_kernel(float* __restrict__ y1,
                                                          const float* __restrict__ sums1,
                                                          const float* __restrict__ g1w,
                                                          const float* __restrict__ g1b,
                                                          const unsigned short* __restrict__ w2b,
                                                          const float* __restrict__ b2,
                                                          float* __restrict__ sums2) {
  __shared__ __align__(16) unsigned short hsm[4][32 * 72];
  __shared__ float sacc[128], qacc[128];
  __shared__ float a1s[64], d1s[64];
  const int tid = threadIdx.x, lane = tid & 63, w = tid >> 6;
  const int wid = blockIdx.x * 4 + w;
  const int b = blockIdx.x >> 8;
  if (tid < 128) { sacc[tid] = 0.0f; qacc[tid] = 0.0f; }
  if (tid < 64) {   // coeffs1 for this b (cpg=2, invn=1/65536)
    int c = tid, g = c >> 1;
    float S = sums1[b * 128 + g * 2] + sums1[b * 128 + g * 2 + 1];
    float Q = sums1[b * 128 + 64 + g * 2] + sums1[b * 128 + 64 + g * 2 + 1];
    float mu = S * (1.0f / 65536.0f);
    float var = Q * (1.0f / 65536.0f) - mu * mu;
    float rs = 1.0f / sqrtf(var + 1e-5f);
    float ga = g1w[c];
    a1s[c] = rs * ga;
    d1s[c] = g1b[c] - mu * rs * ga;
  }
  __syncthreads();
  Conv2Frag F;
  load_w2_frags(w2b, b2, lane, F);
  f32x4 acc[2][8];
  conv2_wave_mfma(y1, a1s, d1s, hsm[w], wid, lane, F, acc);
  const int lr = lane & 15;
  float zmx[8], zmn[8];
  #pragma unroll
  for (int nt = 0; nt < 8; ++nt) {
    float s = 0, q = 0, mx = -3e38f, mn = 3e38f;
    #pragma unroll
    for (int mt = 0; mt < 2; ++mt)
      #pragma unroll
      for (int rg = 0; rg < 4; ++rg) {
        float z = acc[mt][nt][rg] + F.b2v[nt];
        s += z; q = fmaf(z, z, q);
        mx = fmaxf(mx, z); mn = fminf(mn, z);
      }
    atomicAdd(&sacc[nt * 16 + lr], s);
    atomicAdd(&qacc[nt * 16 + lr], q);
    mx = fmaxf(mx, __shfl_xor(mx, 16)); mx = fmaxf(mx, __shfl_xor(mx, 32));
    mn = fminf(mn, __shfl_xor(mn, 16)); mn = fminf(mn, __shfl_xor(mn, 32));
    zmx[nt] = mx; zmn[nt] = mn;
  }
  // store zmax/zmin (f32) into own consumed y1 tile head: [0..127]=max, [128..255]=min
  if (lane < 16) {
    float* zp = y1 + (size_t)wid * 1024;
    #pragma unroll
    for (int nt = 0; nt < 8; ++nt) {
      zp[nt * 16 + lr] = zmx[nt];
      zp[128 + nt * 16 + lr] = zmn[nt];
    }
  }
  __syncthreads();
  if (tid < 128) {
    atomicAdd(&sums2[b * 256 + tid], sacc[tid]);
    atomicAdd(&sums2[b * 256 + 128 + tid], qacc[tid]);
  }
}

// ---------------- K7: final-lite — coeffs2 folded + GN2 affine on zmax/zmin ---
__global__ __launch_bounds__(256) void final_lite(const float* __restrict__ y1,
                                                  const float* __restrict__ sums2,
                                                  const float* __restrict__ g2w,
                                                  const float* __restrict__ g2b,
                                                  float* __restrict__ nf) {
  __shared__ float a2s[128], d2s[128];
  const int tid = threadIdx.x;
  const int wid0 = blockIdx.x * 2;            // 8192 blocks x 2 wids (same b)
  const int b = wid0 >> 10;
  if (tid < 128) {   // coeffs2 for this b (cpg=4, invn=1/131072)
    int c = tid, g = c >> 2;
    float S = ((sums2[b * 256 + g * 4] + sums2[b * 256 + g * 4 + 1])
               + sums2[b * 256 + g * 4 + 2]) + sums2[b * 256 + g * 4 + 3];
    float Q = ((sums2[b * 256 + 128 + g * 4] + sums2[b * 256 + 128 + g * 4 + 1])
               + sums2[b * 256 + 128 + g * 4 + 2]) + sums2[b * 256 + 128 + g * 4 + 3];
    float mu = S * (1.0f / 131072.0f);
    float var = Q * (1.0f / 131072.0f) - mu * mu;
    float rs = 1.0f / sqrtf(var + 1e-5f);
    float ga = g2w[c];
    a2s[c] = rs * ga;
    d2s[c] = g2b[c] - mu * rs * ga;
  }
  __syncthreads();
  int wid = wid0 + (tid >> 7), c = tid & 127;
  const float* zp = y1 + (size_t)wid * 1024;
  float zmx = zp[c];
  float zmn = zp[128 + c];
  float az = a2s[c], dz = d2s[c];
  float z = (az >= 0.0f) ? zmx : zmn;
  nf[(size_t)wid * 128 + c] = fmaxf(0.0f, fmaf(z, az, dz));
}

extern "C" void kernel_launch(void* const* d_in, const int* in_sizes, int n_in,
                              void* d_out, int out_size, void* d_ws, size_t ws_size,
                              hipStream_t stream) {
  const float* xyz  = (const float*)d_in[0];
  const float* feat = (const float*)d_in[1];
  const float* w1   = (const float*)d_in[2];
  const float* b1   = (const float*)d_in[3];
  const float* g1w  = (const float*)d_in[4];
  const float* g1b  = (const float*)d_in[5];
  const float* w2   = (const float*)d_in[6];
  const float* b2   = (const float*)d_in[7];
  const float* g2w  = (const float*)d_in[8];
  const float* g2b  = (const float*)d_in[9];
  float* ws = (float*)d_ws;
  float* cent = (float*)d_out;                    // (B,M,3)
  float* nf   = (float*)d_out + BB * MM * 3;      // (B,M,128)
  const float4* pts4 = (const float4*)(ws + PTS4_OFF);
  int*   knn   = (int*)(ws + KNN_OFF);
  float* sums1 = ws + SUM1_OFF;
  float* sums2 = ws + SUM2_OFF;
  const unsigned short* w2b = (const unsigned short*)(ws + W2B_OFF);
  const unsigned short* w1b = (const unsigned short*)(ws + W1B_OFF);
  const unsigned short* feat16 = (const unsigned short*)(ws + FEAT16_OFF);
  float* y1 = ws + Y1_OFF;

  hipLaunchKernelGGL(fps_init_kernel, dim3(256), dim3(256), 0, stream,
                     xyz, feat, w1, w2, ws, cent);
  hipLaunchKernelGGL(knn_kernel, dim3(256), dim3(512), 0, stream, pts4, cent, knn);
  hipLaunchKernelGGL(conv1_kernel, dim3(4096), dim3(256), 0, stream,
                     xyz, feat16, cent, knn, w1b, b1, y1, sums1);
  hipLaunchKernelGGL(conv2_stats_kernel, dim3(4096), dim3(256), 0, stream,
                     y1, sums1, g1w, g1b, w2b, b2, sums2);
  hipLaunchKernelGGL(final_lite, dim3(8192), dim3(256), 0, stream,
                     y1, sums2, g2w, g2b, nf);
}

// Round 11
// 1402.562 us; speedup vs baseline: 1.1348x; 1.0262x over previous
//
#include <hip/hip_runtime.h>
#include <cstdint>

#define BB 16
#define NN 8192
#define MM 1024
#define KNN 32
#define CIN 64
#define HID 64
#define OCH 128

// workspace float offsets
#define KNN_OFF   0u          // (unused since R10 fusion; kept for layout stability)
#define SUM1_OFF  524288u     // 2048
#define SUM2_OFF  526336u     // 4096
#define W2B_OFF   536576u     // 4096 floats = 8192 bf16 (w2 pre-converted)
#define W1B_OFF   540672u     // 3072 floats = 6144 bf16 (w1 padded 67->96, bf16)
#define Y1_OFF    543744u     // y1 bf16: 16384 tiles x 1024 floats (2048 bf16)
#define PTS4_OFF  Y1_OFF      // 131072 float4 (dead once conv1 runs; knn before conv1)
#define FEAT16_OFF (Y1_OFF + 16777216u)  // feat bf16: 4194304 u32 (8M bf16)

typedef unsigned long long u64;
typedef float f32x4 __attribute__((ext_vector_type(4)));
typedef float f32x2 __attribute__((ext_vector_type(2)));
typedef short bf16x8 __attribute__((ext_vector_type(8)));

__device__ __forceinline__ unsigned short f2bf(float f) {
  union { float f; unsigned u; } v; v.f = f;
  unsigned r = v.u + 0x7FFFu + ((v.u >> 16) & 1u);   // RNE
  return (unsigned short)(r >> 16);
}

__device__ __forceinline__ float bf2f(unsigned short u) {
  return __uint_as_float((unsigned)u << 16);
}

// DPP u64 max-reduction across a wave; full max lands in lane 63.
__device__ __forceinline__ u64 wave_max_u64(u64 v) {
  #define DPP_RND(ctrl, rm)                                                     \
  {                                                                             \
    int lo_ = __builtin_amdgcn_update_dpp(0, (int)(unsigned)(v & 0xFFFFFFFFull),\
                                          ctrl, rm, 0xf, true);                 \
    int hi_ = __builtin_amdgcn_update_dpp(0, (int)(unsigned)(v >> 32),          \
                                          ctrl, rm, 0xf, true);                 \
    u64 o_ = ((u64)(unsigned)hi_ << 32) | (unsigned)lo_;                        \
    v = o_ > v ? o_ : v;                                                        \
  }
  DPP_RND(0x111, 0xf)  // row_shr:1
  DPP_RND(0x112, 0xf)  // row_shr:2
  DPP_RND(0x114, 0xf)  // row_shr:4
  DPP_RND(0x118, 0xf)  // row_shr:8
  DPP_RND(0x142, 0xa)  // row_bcast:15 -> rows 1,3
  DPP_RND(0x143, 0xc)  // row_bcast:31 -> rows 2,3
  #undef DPP_RND
  return v;
}

// ---------------- K1: FPS (blocks 0-15) + init filler (blocks 16-255) ---------
// R9-verified: de-atomized parity wred combine at W=4; fps at its ~800us
// practical floor (issue ~1300cy/step + ~550cy sync/LDS latency @1 wave/SIMD;
// all occupancy/restructure probes R0/R1/R7 regressed — do not touch).
__global__ __launch_bounds__(256) void fps_init_kernel(const float* __restrict__ xyz,
                                                       const float* __restrict__ feat,
                                                       const float* __restrict__ w1,
                                                       const float* __restrict__ w2,
                                                       float* __restrict__ ws,
                                                       float* __restrict__ cent) {
  #pragma clang fp contract(off)
  __shared__ float4 sp4[NN];     // 128 KB
  __shared__ u64 slots[MM];      // 8 KB (replay archive; tid0 plain-stores)
  __shared__ u64 wred[2][4];     // [parity][wave]
  const int tid = threadIdx.x;

  if (blockIdx.x >= 16) {        // ---------- init filler path ----------
    const int t0 = (blockIdx.x - 16) * 256 + tid;
    const int stride = 240 * 256;
    for (int t = t0; t < 12288; t += stride) ws[SUM1_OFF + t] = 0.0f;
    for (int t = t0; t < 4096; t += stride) {   // w2 -> bf16 pairs
      unsigned lo = f2bf(w2[2 * t]);
      unsigned hi = f2bf(w2[2 * t + 1]);
      ((unsigned*)(ws + W2B_OFF))[t] = lo | (hi << 16);
    }
    for (int t = t0; t < 6144; t += stride) {   // w1 padded 67->96 bf16
      int n = t / 96, kk = t % 96;
      float val = 0.0f;
      if (kk < 3) val = w1[n * 67 + kk];
      else if (kk >= 4 && kk < 68) val = w1[n * 67 + kk - 1];
      ((unsigned short*)(ws + W1B_OFF))[t] = f2bf(val);
    }
    for (int t = t0; t < BB * NN; t += stride) {  // pts4 with |p|^2 in w
      float x = xyz[(size_t)t * 3], y = xyz[(size_t)t * 3 + 1], z = xyz[(size_t)t * 3 + 2];
      ((float4*)(ws + PTS4_OFF))[t] = make_float4(x, y, z, (x * x + y * y) + z * z);
    }
    for (int t = t0; t < 4194304; t += stride) {  // feat f32 -> bf16 pairs
      float2 fv = *(const float2*)(feat + 2 * (size_t)t);
      unsigned lo = f2bf(fv.x), hi = f2bf(fv.y);
      ((unsigned*)(ws + FEAT16_OFF))[t] = lo | (hi << 16);
    }
    return;
  }

  // ---------- fps path (4 waves, 1/SIMD; scalar R5-verified math) ----------
  const int b = blockIdx.x;
  const int w = tid >> 6;
  const float* xp = xyz + (size_t)b * NN * 3;
  f32x2 px[16], py[16], pz[16];
  float dist0[16], dist1[16];
  #pragma unroll
  for (int i = 0; i < 16; ++i) {
    int n0 = tid + (2 * i) * 256, n1 = tid + (2 * i + 1) * 256;
    float x0 = xp[n0 * 3], y0 = xp[n0 * 3 + 1], z0 = xp[n0 * 3 + 2];
    float x1 = xp[n1 * 3], y1 = xp[n1 * 3 + 1], z1 = xp[n1 * 3 + 2];
    px[i] = (f32x2){x0, x1}; py[i] = (f32x2){y0, y1}; pz[i] = (f32x2){z0, z1};
    sp4[n0] = make_float4(x0, y0, z0, 0.0f);
    sp4[n1] = make_float4(x1, y1, z1, 0.0f);
    dist0[i] = 1e10f; dist1[i] = 1e10f;
  }
  __syncthreads();
  int far = 0;
  for (int step = 0; step < MM; ++step) {
    float4 c4 = sp4[far];
    f32x2 cx = (f32x2){c4.x, c4.x}, cy = (f32x2){c4.y, c4.y}, cz = (f32x2){c4.z, c4.z};
    float best = -1.0f; int bi = 0;
    #pragma unroll
    for (int i = 0; i < 16; ++i) {
      f32x2 dx = px[i] - cx, dy = py[i] - cy, dz = pz[i] - cz;
      f32x2 d = (dx * dx + dy * dy) + dz * dz;   // np: left-assoc, no fma (per slot)
      float dm0 = fminf(dist0[i], d.x);
      float dm1 = fminf(dist1[i], d.y);
      dist0[i] = dm0; dist1[i] = dm1;
      if (dm0 > best) { best = dm0; bi = tid + (2 * i) * 256; }      // strict >: lowest n
      if (dm1 > best) { best = dm1; bi = tid + (2 * i + 1) * 256; }
    }
    u64 key = ((u64)__float_as_uint(best) << 32) | (unsigned)(8191 - bi);
    key = wave_max_u64(key);
    const int p = step & 1;
    if ((tid & 63) == 63) wred[p][w] = key;      // plain store, no atomic
    __syncthreads();
    u64 k0 = wred[p][0], k1 = wred[p][1], k2 = wred[p][2], k3 = wred[p][3];
    u64 m01 = k0 > k1 ? k0 : k1;
    u64 m23 = k2 > k3 ? k2 : k3;
    u64 bk = m01 > m23 ? m01 : m23;              // commutative max, tie-free keys
    if (tid == 0) slots[step] = bk;              // archive for replay (off-path)
    far = 8191 - (int)(unsigned)(bk & 0xFFFFFFFFull);
  }
  __syncthreads();   // make tid0's slots[] archive visible to all
  // replay: cent[0] = start point 0; cent[s] = winner of step s-1.
  float* co = cent + (size_t)b * MM * 3;
  for (int s = tid; s < MM; s += 256) {
    int fs = (s == 0) ? 0 : (8191 - (int)(unsigned)(slots[s - 1] & 0xFFFFFFFFull));
    float4 c = sp4[fs];
    co[s * 3 + 0] = c.x; co[s * 3 + 1] = c.y; co[s * 3 + 2] = c.z;
  }
}

// ---------------- K2: fused kNN + conv1 ---------------------------------------
// R10: conv1 fused into knn. Phase 1 = verified knn (8-way N-split, bank-free
// buffers, tree merge) — numerics untouched. After the final merge, wave 0
// spills its per-lane 32-NN index lists to LDS (aliases the fully-consumed
// merge area), one barrier, then each of the 8 waves runs the verified conv1
// wave-body for 8 of the block's 64 centroids (w1 frags hoisted, K-pad zeroed
// once per tile, GN1 partial sums accumulated in REGISTERS across rounds ->
// one LDS atomic per channel at the end). Deletes: conv1 launch+gap, knn
// global write+read, 7/8 of stat atomics. GN1 sum ORDER changes only (f32
// noise; R2 precedent). LDS: phase1 64KB reused; phase2 8KB idx + 53.2KB
// tiles = 61.4KB.
__global__ __launch_bounds__(512) void knn_conv1_kernel(const float4* __restrict__ pts4,
                                                        const float* __restrict__ xyz,
                                                        const unsigned short* __restrict__ feat16,
                                                        const float* __restrict__ cent,
                                                        const unsigned short* __restrict__ w1b,
                                                        const float* __restrict__ b1,
                                                        float* __restrict__ y1,
                                                        float* __restrict__ sums1) {
  #pragma clang fp contract(off)
  __shared__ __align__(16) char smem[65536];
  __shared__ float s1acc[64], q1acc[64];
  unsigned* blo = (unsigned*)smem;              // [16][512] cand idx (bank-free)
  unsigned* bhi = (unsigned*)(smem + 32768);    // [16][512] cand key-hi
  u64* marea = (u64*)smem;                      // 4 areas x [32][64]; aliases buffers
                                                // AFTER the post-scan barrier (R5 lesson)
  int* knn_lds = (int*)smem;                    // [64][32] — written by w0 AFTER it
                                                // fully consumed marea(0)
  unsigned short* gsm = (unsigned short*)(smem + 8192);  // 8 tiles x 32*104
  const int tid = threadIdx.x;
  const int lane = tid & 63;
  const int w = tid >> 6;          // wave id = N-octant (phase1) / conv row-group (phase2)
  const int b = blockIdx.x >> 4;
  const int mc = blockIdx.x & 15;
  const int m = (mc << 6) + lane;

  if (tid < 64) { s1acc[tid] = 0.0f; q1acc[tid] = 0.0f; }

  // ===================== PHASE 1: kNN (verified, unchanged) ==================
  const float* cp = cent + ((size_t)b * MM + m) * 3;
  float cx = cp[0], cy = cp[1], cz = cp[2];
  float cn2 = (cx * cx + cy * cy) + cz * cz;
  u64 key[32];
  {
    u64 initk = ((u64)(__float_as_uint(3e38f) ^ 0x80000000u) << 32) | 0xFFFFFFFFull;
    #pragma unroll
    for (int j = 0; j < 32; ++j) key[j] = initk;
  }
  float kthf = 3e38f;

  auto insert = [&](u64 cand) {   // ascending sorted insert, static indexing only
    bool cprev = false; u64 kprev = 0;
    #pragma unroll
    for (int j = 0; j < 32; ++j) {
      bool cj = cand < key[j];
      u64 cur = key[j];
      u64 nv = cj ? cand : cur;
      key[j] = cprev ? kprev : nv;
      cprev = cj; kprev = cur;
    }
    unsigned hb = (unsigned)(key[31] >> 32);
    unsigned ob = (hb & 0x80000000u) ? (hb ^ 0x80000000u) : ~hb;
    kthf = __uint_as_float(ob);
  };

  int cnt = 0;
  auto flush = [&]() {
    int mcx = cnt;
    #pragma unroll
    for (int off = 1; off < 64; off <<= 1) { int o = __shfl_xor(mcx, off); mcx = o > mcx ? o : mcx; }
    for (int i = 0; i < mcx; ++i) {
      u64 cand = ((u64)bhi[i * 512 + tid] << 32) | blo[i * 512 + tid];
      if (i < cnt && cand < key[31]) insert(cand);   // exact (d2,idx) lex decision
    }
    cnt = 0;
  };

  const int nbase = __builtin_amdgcn_readfirstlane(w * 1024);  // force SGPR -> s_load path
  const float4* pb = pts4 + (size_t)b * NN + nbase;
  for (int n0 = 0; n0 < 1024; n0 += 8) {
    #pragma unroll
    for (int j = 0; j < 8; ++j) {
      int n = n0 + j;
      float4 p = pb[n];
      float dot = fmaf(cz, p.z, fmaf(cy, p.y, cx * p.x));  // verified np-exact form
      float d2 = (cn2 + p.w) - 2.0f * dot;                  // separate ufunc ops
      if (d2 <= kthf) {                                     // exact re-check at insert
        unsigned db = __float_as_uint(d2);
        unsigned fk = db ^ (((int)db < 0) ? 0xFFFFFFFFu : 0x80000000u);
        blo[cnt * 512 + tid] = (unsigned)(nbase + n);
        bhi[cnt * 512 + tid] = fk;
        cnt++;
      }
    }
    if (__ballot(cnt >= 9)) flush();   // cap 16: <=8 carried + <=8 new
  }
  flush();
  __syncthreads();   // all waves done scanning; buffers dead -> marea aliasing safe

  auto publish = [&](int a) {
    u64* ap = marea + a * 2048;
    #pragma unroll
    for (int j = 0; j < 32; ++j) ap[j * 64 + lane] = key[j];   // [j][lane]: bank-free
  };
  auto merge_from = [&](int a) {
    u64* ap = marea + a * 2048;
    for (int j = 0; j < 32; ++j) {
      u64 cand = ap[j * 64 + lane];
      if (cand < key[31]) insert(cand);    // exact pairwise min-32 merge
    }
  };
  // tree merge 8->4->2->1 (all barriers at top level)
  if (w & 1) publish(w >> 1);
  __syncthreads();
  if (!(w & 1)) merge_from(w >> 1);
  __syncthreads();
  if (w == 2) publish(0);
  if (w == 6) publish(1);
  __syncthreads();
  if (w == 0) merge_from(0);
  if (w == 4) merge_from(1);
  __syncthreads();
  if (w == 4) publish(0);
  __syncthreads();
  if (w == 0) {
    merge_from(0);
    // spill final per-lane index lists to LDS (marea(0) fully consumed above)
    #pragma unroll
    for (int j = 0; j < 32; ++j)
      knn_lds[lane * 32 + j] = (int)(key[j] & 0xFFFFFFFFull);
  }
  __syncthreads();   // knn_lds visible; phase-1 buffers dead -> gsm aliasing safe

  // ===================== PHASE 2: conv1 (verified wave-body x 8 rounds) ======
  const int quad = lane >> 4, lr = lane & 15;
  unsigned short* gf = gsm + w * (32 * 104);

  // zero K-pad [68..96) once per tile ([64..68) overwritten by feat each round)
  {
    int row = lane >> 1, h = (lane & 1) * 16;
    ushort4 z4 = {0, 0, 0, 0};
    *(ushort4*)(gf + row * 104 + 64 + h + 0)  = z4;
    *(ushort4*)(gf + row * 104 + 64 + h + 4)  = z4;
    *(ushort4*)(gf + row * 104 + 64 + h + 8)  = z4;
    *(ushort4*)(gf + row * 104 + 64 + h + 12) = z4;
  }
  // hoist w1 fragments + bias (same for all rounds)
  bf16x8 bw[4][3];
  float b1v[4];
  #pragma unroll
  for (int nt = 0; nt < 4; ++nt) {
    #pragma unroll
    for (int ks = 0; ks < 3; ++ks)
      bw[nt][ks] = *(const bf16x8*)(w1b + (size_t)(nt * 16 + lr) * 96 + ks * 32 + quad * 8);
    b1v[nt] = b1[nt * 16 + lr];
  }
  float s_nt[4] = {0.f, 0.f, 0.f, 0.f};
  float q_nt[4] = {0.f, 0.f, 0.f, 0.f};
  const unsigned short* fb = feat16 + (size_t)b * NN * 64;

  for (int r = 0; r < 8; ++r) {
    const int lm = w * 8 + r;
    const int wid = b * 1024 + (mc << 6) + lm;
    int idxv = 0;
    if (lane < 32) idxv = knn_lds[lm * 32 + lane];
    // drain prior round's ds_reads before overwriting the tile
    __builtin_amdgcn_s_waitcnt(0);
    __builtin_amdgcn_wave_barrier();
    // delta rows (lanes 0..31): gf[r][0..2] = xyz[idx]-cent, gf[r][3] = dummy 0
    const float* cq = cent + (size_t)wid * 3;
    float ccx = cq[0], ccy = cq[1], ccz = cq[2];
    if (lane < 32) {
      const float* pp = xyz + ((size_t)b * NN + idxv) * 3;
      ushort4 dv;
      dv.x = f2bf(pp[0] - ccx); dv.y = f2bf(pp[1] - ccy); dv.z = f2bf(pp[2] - ccz);
      dv.w = 0;
      *(ushort4*)(gf + lane * 104) = dv;
    }
    // feat: 32 rows x 128B bf16, gathered as 16B units (4 iters/lane)
    #pragma unroll
    for (int i = 0; i < 4; ++i) {
      int v = i * 64 + lane;          // 0..255 units of 16B
      int row = v >> 3, part = v & 7;
      int ridx = __shfl(idxv, row);
      uint4 fv = *(const uint4*)(fb + (size_t)ridx * 64 + part * 8);
      *(uint2*)(gf + row * 104 + 4 + part * 8)     = make_uint2(fv.x, fv.y);
      *(uint2*)(gf + row * 104 + 4 + part * 8 + 4) = make_uint2(fv.z, fv.w);
    }
    __builtin_amdgcn_s_waitcnt(0);
    __builtin_amdgcn_wave_barrier();

    f32x4 acc[2][4];
    #pragma unroll
    for (int mt = 0; mt < 2; ++mt)
      #pragma unroll
      for (int nt = 0; nt < 4; ++nt)
        acc[mt][nt] = (f32x4){0.f, 0.f, 0.f, 0.f};
    #pragma unroll
    for (int ks = 0; ks < 3; ++ks) {
      bf16x8 a0 = *(const bf16x8*)(gf + (0 + lr) * 104 + ks * 32 + quad * 8);
      bf16x8 a1 = *(const bf16x8*)(gf + (16 + lr) * 104 + ks * 32 + quad * 8);
      #pragma unroll
      for (int nt = 0; nt < 4; ++nt) {
        acc[0][nt] = __builtin_amdgcn_mfma_f32_16x16x32_bf16(a0, bw[nt][ks], acc[0][nt], 0, 0, 0);
        acc[1][nt] = __builtin_amdgcn_mfma_f32_16x16x32_bf16(a1, bw[nt][ks], acc[1][nt], 0, 0, 0);
      }
    }
    unsigned short* yo16 = (unsigned short*)(y1 + (size_t)wid * 1024);
    #pragma unroll
    for (int mt = 0; mt < 2; ++mt)
      #pragma unroll
      for (int rg = 0; rg < 4; ++rg) {
        int row = mt * 16 + quad * 4 + rg;
        #pragma unroll
        for (int nt = 0; nt < 4; ++nt) {
          float z = acc[mt][nt][rg] + b1v[nt];
          yo16[row * 64 + nt * 16 + lr] = f2bf(z);
          s_nt[nt] += z;
          q_nt[nt] = fmaf(z, z, q_nt[nt]);
        }
      }
  }
  // quad reduce (lanes lr, lr+16, lr+32, lr+48 hold the 4 row-quarters of ch c)
  #pragma unroll
  for (int nt = 0; nt < 4; ++nt) {
    float s = s_nt[nt], q = q_nt[nt];
    s += __shfl_xor(s, 16); s += __shfl_xor(s, 32);
    q += __shfl_xor(q, 16); q += __shfl_xor(q, 32);
    if (quad == 0) {
      atomicAdd(&s1acc[nt * 16 + lr], s);
      atomicAdd(&q1acc[nt * 16 + lr], q);
    }
  }
  __syncthreads();
  if (tid < 64) {
    atomicAdd(&sums1[b * 128 + tid], s1acc[tid]);
    atomicAdd(&sums1[b * 128 + 64 + tid], q1acc[tid]);
  }
}

// ============ MFMA conv2 common (bf16 y1; a/d from LDS) =======================
struct Conv2Frag {
  bf16x8 bfr[8][2];   // [ntile][kstep]
  float  b2v[8];
};

__device__ __forceinline__ void load_w2_frags(const unsigned short* __restrict__ w2b,
                                              const float* __restrict__ b2,
                                              int lane, Conv2Frag& F) {
  const int quad = lane >> 4, lr = lane & 15;
  #pragma unroll
  for (int nt = 0; nt < 8; ++nt) {
    #pragma unroll
    for (int t = 0; t < 2; ++t)
      F.bfr[nt][t] = *(const bf16x8*)(w2b + (size_t)(nt * 16 + lr) * 64 + t * 32 + quad * 8);
    F.b2v[nt] = b2[nt * 16 + lr];
  }
}

__device__ __forceinline__ void conv2_wave_mfma(const float* __restrict__ y1,
                                                const float* a1s,   // LDS [64]
                                                const float* d1s,   // LDS [64]
                                                unsigned short* __restrict__ hrow, // [32][72]
                                                int wid, int lane,
                                                const Conv2Frag& F,
                                                f32x4 acc[2][8]) {
  const int quad = lane >> 4, lr = lane & 15;
  const int r = lane >> 1, c0 = (lane & 1) * 32;
  const unsigned short* yrow16 =
      (const unsigned short*)(y1 + (size_t)wid * 1024) + r * 64 + c0;
  const float4* ap = (const float4*)(a1s + c0);
  const float4* dp = (const float4*)(d1s + c0);
  #pragma unroll
  for (int gg = 0; gg < 4; ++gg) {
    bf16x8 yv = *(const bf16x8*)(yrow16 + gg * 8);
    float4 av0 = ap[gg * 2],     dv0 = dp[gg * 2];
    float4 av1 = ap[gg * 2 + 1], dv1 = dp[gg * 2 + 1];
    ushort4 s0, s1;
    s0.x = f2bf(fmaxf(0.0f, fmaf(bf2f((unsigned short)yv[0]), av0.x, dv0.x)));
    s0.y = f2bf(fmaxf(0.0f, fmaf(bf2f((unsigned short)yv[1]), av0.y, dv0.y)));
    s0.z = f2bf(fmaxf(0.0f, fmaf(bf2f((unsigned short)yv[2]), av0.z, dv0.z)));
    s0.w = f2bf(fmaxf(0.0f, fmaf(bf2f((unsigned short)yv[3]), av0.w, dv0.w)));
    s1.x = f2bf(fmaxf(0.0f, fmaf(bf2f((unsigned short)yv[4]), av1.x, dv1.x)));
    s1.y = f2bf(fmaxf(0.0f, fmaf(bf2f((unsigned short)yv[5]), av1.y, dv1.y)));
    s1.z = f2bf(fmaxf(0.0f, fmaf(bf2f((unsigned short)yv[6]), av1.z, dv1.z)));
    s1.w = f2bf(fmaxf(0.0f, fmaf(bf2f((unsigned short)yv[7]), av1.w, dv1.w)));
    *(ushort4*)(hrow + r * 72 + c0 + 8 * gg)     = s0;
    *(ushort4*)(hrow + r * 72 + c0 + 8 * gg + 4) = s1;
  }
  __builtin_amdgcn_s_waitcnt(0);            // drain lds writes (same wave consumes)
  __builtin_amdgcn_wave_barrier();
  #pragma unroll
  for (int mt = 0; mt < 2; ++mt)
    #pragma unroll
    for (int nt = 0; nt < 8; ++nt)
      acc[mt][nt] = (f32x4){0.f, 0.f, 0.f, 0.f};
  #pragma unroll
  for (int t = 0; t < 2; ++t) {
    bf16x8 a0 = *(const bf16x8*)(hrow + (0 + lr) * 72 + t * 32 + quad * 8);
    bf16x8 a1f = *(const bf16x8*)(hrow + (16 + lr) * 72 + t * 32 + quad * 8);
    #pragma unroll
    for (int nt = 0; nt < 8; ++nt) {
      acc[0][nt] = __builtin_amdgcn_mfma_f32_16x16x32_bf16(a0,  F.bfr[nt][t], acc[0][nt], 0, 0, 0);
      acc[1][nt] = __builtin_amdgcn_mfma_f32_16x16x32_bf16(a1f, F.bfr[nt][t], acc[1][nt], 0, 0, 0);
    }
  }
}

// ---------------- K5: conv2 (MFMA) -> GN2 stats + zmax/zmin (coeffs1 folded) --
__global__ __launch_bounds__(256) void conv2_stats_kernel(float* __restrict__ y1,
                                                          const float* __restrict__ sums1,
                                                          const float* __restrict__ g1w,
                                                          const float* __restrict__ g1b,
                                                          const unsigned short* __restrict__ w2b,
                                                          const float* __restrict__ b2,
                                                          float* __restrict__ sums2) {
  __shared__ __align__(16) unsigned short hsm[4][32 * 72];
  __shared__ float sacc[128], qacc[128];
  __shared__ float a1s[64], d1s[64];
  const int tid = threadIdx.x, lane = tid & 63, w = tid >> 6;
  const int wid = blockIdx.x * 4 + w;
  const int b = blockIdx.x >> 8;
  if (tid < 128) { sacc[tid] = 0.0f; qacc[tid] = 0.0f; }
  if (tid < 64) {   // coeffs1 for this b (cpg=2, invn=1/65536)
    int c = tid, g = c >> 1;
    float S = sums1[b * 128 + g * 2] + sums1[b * 128 + g * 2 + 1];
    float Q = sums1[b * 128 + 64 + g * 2] + sums1[b * 128 + 64 + g * 2 + 1];
    float mu = S * (1.0f / 65536.0f);
    float var = Q * (1.0f / 65536.0f) - mu * mu;
    float rs = 1.0f / sqrtf(var + 1e-5f);
    float ga = g1w[c];
    a1s[c] = rs * ga;
    d1s[c] = g1b[c] - mu * rs * ga;
  }
  __syncthreads();
  Conv2Frag F;
  load_w2_frags(w2b, b2, lane, F);
  f32x4 acc[2][8];
  conv2_wave_mfma(y1, a1s, d1s, hsm[w], wid, lane, F, acc);
  const int lr = lane & 15;
  float zmx[8], zmn[8];
  #pragma unroll
  for (int nt = 0; nt < 8; ++nt) {
    float s = 0, q = 0, mx = -3e38f, mn = 3e38f;
    #pragma unroll
    for (int mt = 0; mt < 2; ++mt)
      #pragma unroll
      for (int rg = 0; rg < 4; ++rg) {
        float z = acc[mt][nt][rg] + F.b2v[nt];
        s += z; q = fmaf(z, z, q);
        mx = fmaxf(mx, z); mn = fminf(mn, z);
      }
    atomicAdd(&sacc[nt * 16 + lr], s);
    atomicAdd(&qacc[nt * 16 + lr], q);
    mx = fmaxf(mx, __shfl_xor(mx, 16)); mx = fmaxf(mx, __shfl_xor(mx, 32));
    mn = fminf(mn, __shfl_xor(mn, 16)); mn = fminf(mn, __shfl_xor(mn, 32));
    zmx[nt] = mx; zmn[nt] = mn;
  }
  // store zmax/zmin (f32) into own consumed y1 tile head: [0..127]=max, [128..255]=min
  if (lane < 16) {
    float* zp = y1 + (size_t)wid * 1024;
    #pragma unroll
    for (int nt = 0; nt < 8; ++nt) {
      zp[nt * 16 + lr] = zmx[nt];
      zp[128 + nt * 16 + lr] = zmn[nt];
    }
  }
  __syncthreads();
  if (tid < 128) {
    atomicAdd(&sums2[b * 256 + tid], sacc[tid]);
    atomicAdd(&sums2[b * 256 + 128 + tid], qacc[tid]);
  }
}

// ---------------- K7: final-lite — coeffs2 folded + GN2 affine on zmax/zmin ---
__global__ __launch_bounds__(256) void final_lite(const float* __restrict__ y1,
                                                  const float* __restrict__ sums2,
                                                  const float* __restrict__ g2w,
                                                  const float* __restrict__ g2b,
                                                  float* __restrict__ nf) {
  __shared__ float a2s[128], d2s[128];
  const int tid = threadIdx.x;
  const int wid0 = blockIdx.x * 2;            // 8192 blocks x 2 wids (same b)
  const int b = wid0 >> 10;
  if (tid < 128) {   // coeffs2 for this b (cpg=4, invn=1/131072)
    int c = tid, g = c >> 2;
    float S = ((sums2[b * 256 + g * 4] + sums2[b * 256 + g * 4 + 1])
               + sums2[b * 256 + g * 4 + 2]) + sums2[b * 256 + g * 4 + 3];
    float Q = ((sums2[b * 256 + 128 + g * 4] + sums2[b * 256 + 128 + g * 4 + 1])
               + sums2[b * 256 + 128 + g * 4 + 2]) + sums2[b * 256 + 128 + g * 4 + 3];
    float mu = S * (1.0f / 131072.0f);
    float var = Q * (1.0f / 131072.0f) - mu * mu;
    float rs = 1.0f / sqrtf(var + 1e-5f);
    float ga = g2w[c];
    a2s[c] = rs * ga;
    d2s[c] = g2b[c] - mu * rs * ga;
  }
  __syncthreads();
  int wid = wid0 + (tid >> 7), c = tid & 127;
  const float* zp = y1 + (size_t)wid * 1024;
  float zmx = zp[c];
  float zmn = zp[128 + c];
  float az = a2s[c], dz = d2s[c];
  float z = (az >= 0.0f) ? zmx : zmn;
  nf[(size_t)wid * 128 + c] = fmaxf(0.0f, fmaf(z, az, dz));
}

extern "C" void kernel_launch(void* const* d_in, const int* in_sizes, int n_in,
                              void* d_out, int out_size, void* d_ws, size_t ws_size,
                              hipStream_t stream) {
  const float* xyz  = (const float*)d_in[0];
  const float* feat = (const float*)d_in[1];
  const float* w1   = (const float*)d_in[2];
  const float* b1   = (const float*)d_in[3];
  const float* g1w  = (const float*)d_in[4];
  const float* g1b  = (const float*)d_in[5];
  const float* w2   = (const float*)d_in[6];
  const float* b2   = (const float*)d_in[7];
  const float* g2w  = (const float*)d_in[8];
  const float* g2b  = (const float*)d_in[9];
  float* ws = (float*)d_ws;
  float* cent = (float*)d_out;                    // (B,M,3)
  float* nf   = (float*)d_out + BB * MM * 3;      // (B,M,128)
  const float4* pts4 = (const float4*)(ws + PTS4_OFF);
  float* sums1 = ws + SUM1_OFF;
  float* sums2 = ws + SUM2_OFF;
  const unsigned short* w2b = (const unsigned short*)(ws + W2B_OFF);
  const unsigned short* w1b = (const unsigned short*)(ws + W1B_OFF);
  const unsigned short* feat16 = (const unsigned short*)(ws + FEAT16_OFF);
  float* y1 = ws + Y1_OFF;

  hipLaunchKernelGGL(fps_init_kernel, dim3(256), dim3(256), 0, stream,
                     xyz, feat, w1, w2, ws, cent);
  hipLaunchKernelGGL(knn_conv1_kernel, dim3(256), dim3(512), 0, stream,
                     pts4, xyz, feat16, cent, w1b, b1, y1, sums1);
  hipLaunchKernelGGL(conv2_stats_kernel, dim3(4096), dim3(256), 0, stream,
                     y1, sums1, g1w, g1b, w2b, b2, sums2);
  hipLaunchKernelGGL(final_lite, dim3(8192), dim3(256), 0, stream,
                     y1, sums2, g2w, g2b, nf);
}

// Round 12
// 1372.406 us; speedup vs baseline: 1.1597x; 1.0220x over previous
//
#include <hip/hip_runtime.h>
#include <cstdint>

#define BB 16
#define NN 8192
#define MM 1024
#define KNN 32
#define CIN 64
#define HID 64
#define OCH 128

// workspace float offsets
#define SUM1_OFF  524288u     // 2048
#define SUM2_OFF  526336u     // 4096
#define CNT_OFF   530432u     // 32 ints (per-b phase counters) — inside zeroed window
#define W2B_OFF   536576u     // 4096 floats = 8192 bf16 (w2 pre-converted)
#define W1B_OFF   540672u     // 3072 floats = 6144 bf16 (w1 padded 67->96, bf16)
#define Y1_OFF    543744u     // y1 bf16: 16384 tiles x 1024 floats (2048 bf16)
#define PTS4_OFF  Y1_OFF      // 131072 float4 (dead once conv1 runs; knn before conv1)
#define FEAT16_OFF (Y1_OFF + 16777216u)  // feat bf16: 4194304 u32 (8M bf16)

typedef unsigned long long u64;
typedef float f32x4 __attribute__((ext_vector_type(4)));
typedef float f32x2 __attribute__((ext_vector_type(2)));
typedef short bf16x8 __attribute__((ext_vector_type(8)));

__device__ __forceinline__ unsigned short f2bf(float f) {
  union { float f; unsigned u; } v; v.f = f;
  unsigned r = v.u + 0x7FFFu + ((v.u >> 16) & 1u);   // RNE
  return (unsigned short)(r >> 16);
}

__device__ __forceinline__ float bf2f(unsigned short u) {
  return __uint_as_float((unsigned)u << 16);
}

// DPP u64 max-reduction across a wave; full max lands in lane 63.
__device__ __forceinline__ u64 wave_max_u64(u64 v) {
  #define DPP_RND(ctrl, rm)                                                     \
  {                                                                             \
    int lo_ = __builtin_amdgcn_update_dpp(0, (int)(unsigned)(v & 0xFFFFFFFFull),\
                                          ctrl, rm, 0xf, true);                 \
    int hi_ = __builtin_amdgcn_update_dpp(0, (int)(unsigned)(v >> 32),          \
                                          ctrl, rm, 0xf, true);                 \
    u64 o_ = ((u64)(unsigned)hi_ << 32) | (unsigned)lo_;                        \
    v = o_ > v ? o_ : v;                                                        \
  }
  DPP_RND(0x111, 0xf)  // row_shr:1
  DPP_RND(0x112, 0xf)  // row_shr:2
  DPP_RND(0x114, 0xf)  // row_shr:4
  DPP_RND(0x118, 0xf)  // row_shr:8
  DPP_RND(0x142, 0xa)  // row_bcast:15 -> rows 1,3
  DPP_RND(0x143, 0xc)  // row_bcast:31 -> rows 2,3
  #undef DPP_RND
  return v;
}

// ---------------- K1: FPS (blocks 0-15) + init filler (blocks 16-255) ---------
// R9-verified; fps at its ~800us practical floor — do not touch.
__global__ __launch_bounds__(256) void fps_init_kernel(const float* __restrict__ xyz,
                                                       const float* __restrict__ feat,
                                                       const float* __restrict__ w1,
                                                       const float* __restrict__ w2,
                                                       float* __restrict__ ws,
                                                       float* __restrict__ cent) {
  #pragma clang fp contract(off)
  __shared__ float4 sp4[NN];     // 128 KB
  __shared__ u64 slots[MM];      // 8 KB (replay archive; tid0 plain-stores)
  __shared__ u64 wred[2][4];     // [parity][wave]
  const int tid = threadIdx.x;

  if (blockIdx.x >= 16) {        // ---------- init filler path ----------
    const int t0 = (blockIdx.x - 16) * 256 + tid;
    const int stride = 240 * 256;
    for (int t = t0; t < 12288; t += stride) ws[SUM1_OFF + t] = 0.0f;  // sums + counters
    for (int t = t0; t < 4096; t += stride) {   // w2 -> bf16 pairs
      unsigned lo = f2bf(w2[2 * t]);
      unsigned hi = f2bf(w2[2 * t + 1]);
      ((unsigned*)(ws + W2B_OFF))[t] = lo | (hi << 16);
    }
    for (int t = t0; t < 6144; t += stride) {   // w1 padded 67->96 bf16
      int n = t / 96, kk = t % 96;
      float val = 0.0f;
      if (kk < 3) val = w1[n * 67 + kk];
      else if (kk >= 4 && kk < 68) val = w1[n * 67 + kk - 1];
      ((unsigned short*)(ws + W1B_OFF))[t] = f2bf(val);
    }
    for (int t = t0; t < BB * NN; t += stride) {  // pts4 with |p|^2 in w
      float x = xyz[(size_t)t * 3], y = xyz[(size_t)t * 3 + 1], z = xyz[(size_t)t * 3 + 2];
      ((float4*)(ws + PTS4_OFF))[t] = make_float4(x, y, z, (x * x + y * y) + z * z);
    }
    for (int t = t0; t < 4194304; t += stride) {  // feat f32 -> bf16 pairs
      float2 fv = *(const float2*)(feat + 2 * (size_t)t);
      unsigned lo = f2bf(fv.x), hi = f2bf(fv.y);
      ((unsigned*)(ws + FEAT16_OFF))[t] = lo | (hi << 16);
    }
    return;
  }

  // ---------- fps path (4 waves, 1/SIMD; scalar R5-verified math) ----------
  const int b = blockIdx.x;
  const int w = tid >> 6;
  const float* xp = xyz + (size_t)b * NN * 3;
  f32x2 px[16], py[16], pz[16];
  float dist0[16], dist1[16];
  #pragma unroll
  for (int i = 0; i < 16; ++i) {
    int n0 = tid + (2 * i) * 256, n1 = tid + (2 * i + 1) * 256;
    float x0 = xp[n0 * 3], y0 = xp[n0 * 3 + 1], z0 = xp[n0 * 3 + 2];
    float x1 = xp[n1 * 3], y1 = xp[n1 * 3 + 1], z1 = xp[n1 * 3 + 2];
    px[i] = (f32x2){x0, x1}; py[i] = (f32x2){y0, y1}; pz[i] = (f32x2){z0, z1};
    sp4[n0] = make_float4(x0, y0, z0, 0.0f);
    sp4[n1] = make_float4(x1, y1, z1, 0.0f);
    dist0[i] = 1e10f; dist1[i] = 1e10f;
  }
  __syncthreads();
  int far = 0;
  for (int step = 0; step < MM; ++step) {
    float4 c4 = sp4[far];
    f32x2 cx = (f32x2){c4.x, c4.x}, cy = (f32x2){c4.y, c4.y}, cz = (f32x2){c4.z, c4.z};
    float best = -1.0f; int bi = 0;
    #pragma unroll
    for (int i = 0; i < 16; ++i) {
      f32x2 dx = px[i] - cx, dy = py[i] - cy, dz = pz[i] - cz;
      f32x2 d = (dx * dx + dy * dy) + dz * dz;   // np: left-assoc, no fma (per slot)
      float dm0 = fminf(dist0[i], d.x);
      float dm1 = fminf(dist1[i], d.y);
      dist0[i] = dm0; dist1[i] = dm1;
      if (dm0 > best) { best = dm0; bi = tid + (2 * i) * 256; }      // strict >: lowest n
      if (dm1 > best) { best = dm1; bi = tid + (2 * i + 1) * 256; }
    }
    u64 key = ((u64)__float_as_uint(best) << 32) | (unsigned)(8191 - bi);
    key = wave_max_u64(key);
    const int p = step & 1;
    if ((tid & 63) == 63) wred[p][w] = key;      // plain store, no atomic
    __syncthreads();
    u64 k0 = wred[p][0], k1 = wred[p][1], k2 = wred[p][2], k3 = wred[p][3];
    u64 m01 = k0 > k1 ? k0 : k1;
    u64 m23 = k2 > k3 ? k2 : k3;
    u64 bk = m01 > m23 ? m01 : m23;              // commutative max, tie-free keys
    if (tid == 0) slots[step] = bk;              // archive for replay (off-path)
    far = 8191 - (int)(unsigned)(bk & 0xFFFFFFFFull);
  }
  __syncthreads();   // make tid0's slots[] archive visible to all
  // replay: cent[0] = start point 0; cent[s] = winner of step s-1.
  float* co = cent + (size_t)b * MM * 3;
  for (int s = tid; s < MM; s += 256) {
    int fs = (s == 0) ? 0 : (8191 - (int)(unsigned)(slots[s - 1] & 0xFFFFFFFFull));
    float4 c = sp4[fs];
    co[s * 3 + 0] = c.x; co[s * 3 + 1] = c.y; co[s * 3 + 2] = c.z;
  }
}

// ============ MFMA conv2 common (bf16 y1; a/d from LDS) =======================
struct Conv2Frag {
  bf16x8 bfr[8][2];   // [ntile][kstep]
  float  b2v[8];
};

__device__ __forceinline__ void load_w2_frags(const unsigned short* __restrict__ w2b,
                                              const float* __restrict__ b2,
                                              int lane, Conv2Frag& F) {
  const int quad = lane >> 4, lr = lane & 15;
  #pragma unroll
  for (int nt = 0; nt < 8; ++nt) {
    #pragma unroll
    for (int t = 0; t < 2; ++t)
      F.bfr[nt][t] = *(const bf16x8*)(w2b + (size_t)(nt * 16 + lr) * 64 + t * 32 + quad * 8);
    F.b2v[nt] = b2[nt * 16 + lr];
  }
}

__device__ __forceinline__ void conv2_wave_mfma(const float* __restrict__ y1,
                                                const float* a1s,   // LDS [64]
                                                const float* d1s,   // LDS [64]
                                                unsigned short* __restrict__ hrow, // [32][72]
                                                int wid, int lane,
                                                const Conv2Frag& F,
                                                f32x4 acc[2][8]) {
  const int quad = lane >> 4, lr = lane & 15;
  const int r = lane >> 1, c0 = (lane & 1) * 32;
  const unsigned short* yrow16 =
      (const unsigned short*)(y1 + (size_t)wid * 1024) + r * 64 + c0;
  const float4* ap = (const float4*)(a1s + c0);
  const float4* dp = (const float4*)(d1s + c0);
  #pragma unroll
  for (int gg = 0; gg < 4; ++gg) {
    bf16x8 yv = *(const bf16x8*)(yrow16 + gg * 8);
    float4 av0 = ap[gg * 2],     dv0 = dp[gg * 2];
    float4 av1 = ap[gg * 2 + 1], dv1 = dp[gg * 2 + 1];
    ushort4 s0, s1;
    s0.x = f2bf(fmaxf(0.0f, fmaf(bf2f((unsigned short)yv[0]), av0.x, dv0.x)));
    s0.y = f2bf(fmaxf(0.0f, fmaf(bf2f((unsigned short)yv[1]), av0.y, dv0.y)));
    s0.z = f2bf(fmaxf(0.0f, fmaf(bf2f((unsigned short)yv[2]), av0.z, dv0.z)));
    s0.w = f2bf(fmaxf(0.0f, fmaf(bf2f((unsigned short)yv[3]), av0.w, dv0.w)));
    s1.x = f2bf(fmaxf(0.0f, fmaf(bf2f((unsigned short)yv[4]), av1.x, dv1.x)));
    s1.y = f2bf(fmaxf(0.0f, fmaf(bf2f((unsigned short)yv[5]), av1.y, dv1.y)));
    s1.z = f2bf(fmaxf(0.0f, fmaf(bf2f((unsigned short)yv[6]), av1.z, dv1.z)));
    s1.w = f2bf(fmaxf(0.0f, fmaf(bf2f((unsigned short)yv[7]), av1.w, dv1.w)));
    *(ushort4*)(hrow + r * 72 + c0 + 8 * gg)     = s0;
    *(ushort4*)(hrow + r * 72 + c0 + 8 * gg + 4) = s1;
  }
  __builtin_amdgcn_s_waitcnt(0);            // drain lds writes (same wave consumes)
  __builtin_amdgcn_wave_barrier();
  #pragma unroll
  for (int mt = 0; mt < 2; ++mt)
    #pragma unroll
    for (int nt = 0; nt < 8; ++nt)
      acc[mt][nt] = (f32x4){0.f, 0.f, 0.f, 0.f};
  #pragma unroll
  for (int t = 0; t < 2; ++t) {
    bf16x8 a0 = *(const bf16x8*)(hrow + (0 + lr) * 72 + t * 32 + quad * 8);
    bf16x8 a1f = *(const bf16x8*)(hrow + (16 + lr) * 72 + t * 32 + quad * 8);
    #pragma unroll
    for (int nt = 0; nt < 8; ++nt) {
      acc[0][nt] = __builtin_amdgcn_mfma_f32_16x16x32_bf16(a0,  F.bfr[nt][t], acc[0][nt], 0, 0, 0);
      acc[1][nt] = __builtin_amdgcn_mfma_f32_16x16x32_bf16(a1f, F.bfr[nt][t], acc[1][nt], 0, 0, 0);
    }
  }
}

// ---------------- K2: fused kNN + conv1 + conv2/GN2-stats + final -------------
// R12: the whole mid-pipeline in ONE kernel. Cross-block deps are ONLY the
// per-batch GN sums; each batch b is covered by exactly 16 blocks of this
// 256-block grid (all co-resident at 1 block/CU on 256 CUs), so a per-b
// device-scope counter barrier (release-add after sums atomics; acquire-spin
// until 16; G16 pattern) replaces the kernel boundaries. conv2 reads only the
// y1 tiles THIS block wrote (block-local, L1/L2-hot); zmax/zmin go to the own
// y1 tile heads (block-local). Spin is bounded for hang safety. Deletes 2
// launches + gaps + cross-kernel y1 re-read. Numerics: knn/conv1/conv2 bodies
// identical to R11; GN sum order changes only (already nondeterministic).
__global__ __launch_bounds__(512) void mega_kernel(const float4* __restrict__ pts4,
                                                   const float* __restrict__ xyz,
                                                   const unsigned short* __restrict__ feat16,
                                                   const float* __restrict__ cent,
                                                   const unsigned short* __restrict__ w1b,
                                                   const float* __restrict__ b1,
                                                   const unsigned short* __restrict__ w2b,
                                                   const float* __restrict__ b2,
                                                   const float* __restrict__ g1w,
                                                   const float* __restrict__ g1b,
                                                   const float* __restrict__ g2w,
                                                   const float* __restrict__ g2b,
                                                   float* __restrict__ y1,
                                                   float* __restrict__ sums1,
                                                   float* __restrict__ sums2,
                                                   int* __restrict__ cnt,
                                                   float* __restrict__ nf) {
  #pragma clang fp contract(off)
  __shared__ __align__(16) char smem[65536];
  __shared__ float s1acc[64], q1acc[64];
  __shared__ float sacc[128], qacc[128];
  __shared__ float a1s[64], d1s[64];
  __shared__ float a2s[128], d2s[128];
  unsigned* blo = (unsigned*)smem;              // [16][512] cand idx (bank-free)
  unsigned* bhi = (unsigned*)(smem + 32768);    // [16][512] cand key-hi
  u64* marea = (u64*)smem;                      // 4 areas x [32][64]; aliases buffers
  int* knn_lds = (int*)smem;                    // [64][32] — w0 writes AFTER consuming marea(0)
  unsigned short* gsm = (unsigned short*)(smem + 8192);  // 8 tiles x 32*104 (phase 2)
  const int tid = threadIdx.x;
  const int lane = tid & 63;
  const int w = tid >> 6;
  const int b = blockIdx.x >> 4;
  const int mc = blockIdx.x & 15;
  const int m = (mc << 6) + lane;

  if (tid < 64) { s1acc[tid] = 0.0f; q1acc[tid] = 0.0f; }
  if (tid < 128) { sacc[tid] = 0.0f; qacc[tid] = 0.0f; }

  // ===================== PHASE 1: kNN (verified, unchanged) ==================
  const float* cp = cent + ((size_t)b * MM + m) * 3;
  float cx = cp[0], cy = cp[1], cz = cp[2];
  float cn2 = (cx * cx + cy * cy) + cz * cz;
  u64 key[32];
  {
    u64 initk = ((u64)(__float_as_uint(3e38f) ^ 0x80000000u) << 32) | 0xFFFFFFFFull;
    #pragma unroll
    for (int j = 0; j < 32; ++j) key[j] = initk;
  }
  float kthf = 3e38f;

  auto insert = [&](u64 cand) {   // ascending sorted insert, static indexing only
    bool cprev = false; u64 kprev = 0;
    #pragma unroll
    for (int j = 0; j < 32; ++j) {
      bool cj = cand < key[j];
      u64 cur = key[j];
      u64 nv = cj ? cand : cur;
      key[j] = cprev ? kprev : nv;
      cprev = cj; kprev = cur;
    }
    unsigned hb = (unsigned)(key[31] >> 32);
    unsigned ob = (hb & 0x80000000u) ? (hb ^ 0x80000000u) : ~hb;
    kthf = __uint_as_float(ob);
  };

  int cntl = 0;
  auto flush = [&]() {
    int mcx = cntl;
    #pragma unroll
    for (int off = 1; off < 64; off <<= 1) { int o = __shfl_xor(mcx, off); mcx = o > mcx ? o : mcx; }
    for (int i = 0; i < mcx; ++i) {
      u64 cand = ((u64)bhi[i * 512 + tid] << 32) | blo[i * 512 + tid];
      if (i < cntl && cand < key[31]) insert(cand);   // exact (d2,idx) lex decision
    }
    cntl = 0;
  };

  const int nbase = __builtin_amdgcn_readfirstlane(w * 1024);  // force SGPR -> s_load path
  const float4* pb = pts4 + (size_t)b * NN + nbase;
  for (int n0 = 0; n0 < 1024; n0 += 8) {
    #pragma unroll
    for (int j = 0; j < 8; ++j) {
      int n = n0 + j;
      float4 p = pb[n];
      float dot = fmaf(cz, p.z, fmaf(cy, p.y, cx * p.x));  // verified np-exact form
      float d2 = (cn2 + p.w) - 2.0f * dot;                  // separate ufunc ops
      if (d2 <= kthf) {                                     // exact re-check at insert
        unsigned db = __float_as_uint(d2);
        unsigned fk = db ^ (((int)db < 0) ? 0xFFFFFFFFu : 0x80000000u);
        blo[cntl * 512 + tid] = (unsigned)(nbase + n);
        bhi[cntl * 512 + tid] = fk;
        cntl++;
      }
    }
    if (__ballot(cntl >= 9)) flush();   // cap 16: <=8 carried + <=8 new
  }
  flush();
  __syncthreads();   // all waves done scanning; buffers dead -> marea aliasing safe

  auto publish = [&](int a) {
    u64* ap = marea + a * 2048;
    #pragma unroll
    for (int j = 0; j < 32; ++j) ap[j * 64 + lane] = key[j];   // [j][lane]: bank-free
  };
  auto merge_from = [&](int a) {
    u64* ap = marea + a * 2048;
    for (int j = 0; j < 32; ++j) {
      u64 cand = ap[j * 64 + lane];
      if (cand < key[31]) insert(cand);    // exact pairwise min-32 merge
    }
  };
  // tree merge 8->4->2->1 (all barriers at top level)
  if (w & 1) publish(w >> 1);
  __syncthreads();
  if (!(w & 1)) merge_from(w >> 1);
  __syncthreads();
  if (w == 2) publish(0);
  if (w == 6) publish(1);
  __syncthreads();
  if (w == 0) merge_from(0);
  if (w == 4) merge_from(1);
  __syncthreads();
  if (w == 4) publish(0);
  __syncthreads();
  if (w == 0) {
    merge_from(0);
    #pragma unroll
    for (int j = 0; j < 32; ++j)
      knn_lds[lane * 32 + j] = (int)(key[j] & 0xFFFFFFFFull);
  }
  __syncthreads();   // knn_lds visible; phase-1 buffers dead -> gsm aliasing safe

  // ===================== PHASE 2: conv1 (verified wave-body x 8 rounds) ======
  const int quad = lane >> 4, lr = lane & 15;
  unsigned short* gf = gsm + w * (32 * 104);

  {
    int row = lane >> 1, h = (lane & 1) * 16;
    ushort4 z4 = {0, 0, 0, 0};
    *(ushort4*)(gf + row * 104 + 64 + h + 0)  = z4;
    *(ushort4*)(gf + row * 104 + 64 + h + 4)  = z4;
    *(ushort4*)(gf + row * 104 + 64 + h + 8)  = z4;
    *(ushort4*)(gf + row * 104 + 64 + h + 12) = z4;
  }
  bf16x8 bw[4][3];
  float b1v[4];
  #pragma unroll
  for (int nt = 0; nt < 4; ++nt) {
    #pragma unroll
    for (int ks = 0; ks < 3; ++ks)
      bw[nt][ks] = *(const bf16x8*)(w1b + (size_t)(nt * 16 + lr) * 96 + ks * 32 + quad * 8);
    b1v[nt] = b1[nt * 16 + lr];
  }
  float s_nt[4] = {0.f, 0.f, 0.f, 0.f};
  float q_nt[4] = {0.f, 0.f, 0.f, 0.f};
  const unsigned short* fb = feat16 + (size_t)b * NN * 64;

  for (int r = 0; r < 8; ++r) {
    const int lm = w * 8 + r;
    const int wid = b * 1024 + (mc << 6) + lm;
    int idxv = 0;
    if (lane < 32) idxv = knn_lds[lm * 32 + lane];
    __builtin_amdgcn_s_waitcnt(0);
    __builtin_amdgcn_wave_barrier();
    const float* cq = cent + (size_t)wid * 3;
    float ccx = cq[0], ccy = cq[1], ccz = cq[2];
    if (lane < 32) {
      const float* pp = xyz + ((size_t)b * NN + idxv) * 3;
      ushort4 dv;
      dv.x = f2bf(pp[0] - ccx); dv.y = f2bf(pp[1] - ccy); dv.z = f2bf(pp[2] - ccz);
      dv.w = 0;
      *(ushort4*)(gf + lane * 104) = dv;
    }
    #pragma unroll
    for (int i = 0; i < 4; ++i) {
      int v = i * 64 + lane;
      int row = v >> 3, part = v & 7;
      int ridx = __shfl(idxv, row);
      uint4 fv = *(const uint4*)(fb + (size_t)ridx * 64 + part * 8);
      *(uint2*)(gf + row * 104 + 4 + part * 8)     = make_uint2(fv.x, fv.y);
      *(uint2*)(gf + row * 104 + 4 + part * 8 + 4) = make_uint2(fv.z, fv.w);
    }
    __builtin_amdgcn_s_waitcnt(0);
    __builtin_amdgcn_wave_barrier();

    f32x4 acc[2][4];
    #pragma unroll
    for (int mt = 0; mt < 2; ++mt)
      #pragma unroll
      for (int nt = 0; nt < 4; ++nt)
        acc[mt][nt] = (f32x4){0.f, 0.f, 0.f, 0.f};
    #pragma unroll
    for (int ks = 0; ks < 3; ++ks) {
      bf16x8 a0 = *(const bf16x8*)(gf + (0 + lr) * 104 + ks * 32 + quad * 8);
      bf16x8 a1 = *(const bf16x8*)(gf + (16 + lr) * 104 + ks * 32 + quad * 8);
      #pragma unroll
      for (int nt = 0; nt < 4; ++nt) {
        acc[0][nt] = __builtin_amdgcn_mfma_f32_16x16x32_bf16(a0, bw[nt][ks], acc[0][nt], 0, 0, 0);
        acc[1][nt] = __builtin_amdgcn_mfma_f32_16x16x32_bf16(a1, bw[nt][ks], acc[1][nt], 0, 0, 0);
      }
    }
    unsigned short* yo16 = (unsigned short*)(y1 + (size_t)wid * 1024);
    #pragma unroll
    for (int mt = 0; mt < 2; ++mt)
      #pragma unroll
      for (int rg = 0; rg < 4; ++rg) {
        int row = mt * 16 + quad * 4 + rg;
        #pragma unroll
        for (int nt = 0; nt < 4; ++nt) {
          float z = acc[mt][nt][rg] + b1v[nt];
          yo16[row * 64 + nt * 16 + lr] = f2bf(z);
          s_nt[nt] += z;
          q_nt[nt] = fmaf(z, z, q_nt[nt]);
        }
      }
  }
  #pragma unroll
  for (int nt = 0; nt < 4; ++nt) {
    float s = s_nt[nt], q = q_nt[nt];
    s += __shfl_xor(s, 16); s += __shfl_xor(s, 32);
    q += __shfl_xor(q, 16); q += __shfl_xor(q, 32);
    if (quad == 0) {
      atomicAdd(&s1acc[nt * 16 + lr], s);
      atomicAdd(&q1acc[nt * 16 + lr], q);
    }
  }
  __syncthreads();
  if (tid < 64) {
    atomicAdd(&sums1[b * 128 + tid], s1acc[tid]);
    atomicAdd(&sums1[b * 128 + 64 + tid], q1acc[tid]);
  }
  __syncthreads();   // all sums1 atomics issued & drained (vmcnt per-wave)

  // ---- per-b barrier #1 (16 sibling blocks) ----
  if (tid == 0) {
    __threadfence();
    __hip_atomic_fetch_add(&cnt[b], 1, __ATOMIC_RELEASE, __HIP_MEMORY_SCOPE_AGENT);
    for (long it = 0; it < (1L << 30); ++it) {
      if (__hip_atomic_load(&cnt[b], __ATOMIC_ACQUIRE, __HIP_MEMORY_SCOPE_AGENT) >= 16) break;
      __builtin_amdgcn_s_sleep(2);
    }
  }
  __syncthreads();

  // coeffs1 for this b (cpg=2, invn=1/65536) — atomic loads bypass stale L1
  if (tid < 64) {
    int c = tid, g = c >> 1;
    float S = __hip_atomic_load(&sums1[b * 128 + g * 2], __ATOMIC_RELAXED, __HIP_MEMORY_SCOPE_AGENT)
            + __hip_atomic_load(&sums1[b * 128 + g * 2 + 1], __ATOMIC_RELAXED, __HIP_MEMORY_SCOPE_AGENT);
    float Q = __hip_atomic_load(&sums1[b * 128 + 64 + g * 2], __ATOMIC_RELAXED, __HIP_MEMORY_SCOPE_AGENT)
            + __hip_atomic_load(&sums1[b * 128 + 64 + g * 2 + 1], __ATOMIC_RELAXED, __HIP_MEMORY_SCOPE_AGENT);
    float mu = S * (1.0f / 65536.0f);
    float var = Q * (1.0f / 65536.0f) - mu * mu;
    float rs = 1.0f / sqrtf(var + 1e-5f);
    float ga = g1w[c];
    a1s[c] = rs * ga;
    d1s[c] = g1b[c] - mu * rs * ga;
  }
  __syncthreads();   // a1s/d1s ready; gsm dead -> hrow aliasing safe

  // ===================== PHASE 3: conv2 + GN2 stats + zmax/zmin ==============
  unsigned short* hrow = (unsigned short*)smem + w * 2304;   // 32*72 per wave
  Conv2Frag F;
  load_w2_frags(w2b, b2, lane, F);
  float s2_nt[8] = {0, 0, 0, 0, 0, 0, 0, 0};
  float q2_nt[8] = {0, 0, 0, 0, 0, 0, 0, 0};
  for (int r = 0; r < 8; ++r) {
    const int wid = b * 1024 + (mc << 6) + w * 8 + r;
    f32x4 acc[2][8];
    conv2_wave_mfma(y1, a1s, d1s, hrow, wid, lane, F, acc);
    float zmx[8], zmn[8];
    #pragma unroll
    for (int nt = 0; nt < 8; ++nt) {
      float s = 0, q = 0, mx = -3e38f, mn = 3e38f;
      #pragma unroll
      for (int mt = 0; mt < 2; ++mt)
        #pragma unroll
        for (int rg = 0; rg < 4; ++rg) {
          float z = acc[mt][nt][rg] + F.b2v[nt];
          s += z; q = fmaf(z, z, q);
          mx = fmaxf(mx, z); mn = fminf(mn, z);
        }
      s2_nt[nt] += s; q2_nt[nt] += q;
      mx = fmaxf(mx, __shfl_xor(mx, 16)); mx = fmaxf(mx, __shfl_xor(mx, 32));
      mn = fminf(mn, __shfl_xor(mn, 16)); mn = fminf(mn, __shfl_xor(mn, 32));
      zmx[nt] = mx; zmn[nt] = mn;
    }
    // own tile head (fully consumed above): [0..127]=max, [128..255]=min
    if (lane < 16) {
      float* zp = y1 + (size_t)wid * 1024;
      #pragma unroll
      for (int nt = 0; nt < 8; ++nt) {
        zp[nt * 16 + lr] = zmx[nt];
        zp[128 + nt * 16 + lr] = zmn[nt];
      }
    }
    // ensure this round's tr reads done before next round reuses hrow
    __builtin_amdgcn_s_waitcnt(0);
    __builtin_amdgcn_wave_barrier();
  }
  // quad-reduce s2/q2 across lane groups (lr, lr+16, lr+32, lr+48)
  #pragma unroll
  for (int nt = 0; nt < 8; ++nt) {
    float s = s2_nt[nt], q = q2_nt[nt];
    s += __shfl_xor(s, 16); s += __shfl_xor(s, 32);
    q += __shfl_xor(q, 16); q += __shfl_xor(q, 32);
    if (quad == 0) {
      atomicAdd(&sacc[nt * 16 + lr], s);
      atomicAdd(&qacc[nt * 16 + lr], q);
    }
  }
  __syncthreads();
  if (tid < 128) {
    atomicAdd(&sums2[b * 256 + tid], sacc[tid]);
    atomicAdd(&sums2[b * 256 + 128 + tid], qacc[tid]);
  }
  __syncthreads();

  // ---- per-b barrier #2 ----
  if (tid == 0) {
    __threadfence();
    __hip_atomic_fetch_add(&cnt[16 + b], 1, __ATOMIC_RELEASE, __HIP_MEMORY_SCOPE_AGENT);
    for (long it = 0; it < (1L << 30); ++it) {
      if (__hip_atomic_load(&cnt[16 + b], __ATOMIC_ACQUIRE, __HIP_MEMORY_SCOPE_AGENT) >= 16) break;
      __builtin_amdgcn_s_sleep(2);
    }
  }
  __syncthreads();

  // coeffs2 for this b (cpg=4, invn=1/131072) — same add order as before
  if (tid < 128) {
    int c = tid, g = c >> 2;
    float s0 = __hip_atomic_load(&sums2[b * 256 + g * 4],     __ATOMIC_RELAXED, __HIP_MEMORY_SCOPE_AGENT);
    float s1 = __hip_atomic_load(&sums2[b * 256 + g * 4 + 1], __ATOMIC_RELAXED, __HIP_MEMORY_SCOPE_AGENT);
    float s2 = __hip_atomic_load(&sums2[b * 256 + g * 4 + 2], __ATOMIC_RELAXED, __HIP_MEMORY_SCOPE_AGENT);
    float s3 = __hip_atomic_load(&sums2[b * 256 + g * 4 + 3], __ATOMIC_RELAXED, __HIP_MEMORY_SCOPE_AGENT);
    float q0 = __hip_atomic_load(&sums2[b * 256 + 128 + g * 4],     __ATOMIC_RELAXED, __HIP_MEMORY_SCOPE_AGENT);
    float q1 = __hip_atomic_load(&sums2[b * 256 + 128 + g * 4 + 1], __ATOMIC_RELAXED, __HIP_MEMORY_SCOPE_AGENT);
    float q2 = __hip_atomic_load(&sums2[b * 256 + 128 + g * 4 + 2], __ATOMIC_RELAXED, __HIP_MEMORY_SCOPE_AGENT);
    float q3 = __hip_atomic_load(&sums2[b * 256 + 128 + g * 4 + 3], __ATOMIC_RELAXED, __HIP_MEMORY_SCOPE_AGENT);
    float S = ((s0 + s1) + s2) + s3;
    float Q = ((q0 + q1) + q2) + q3;
    float mu = S * (1.0f / 131072.0f);
    float var = Q * (1.0f / 131072.0f) - mu * mu;
    float rs = 1.0f / sqrtf(var + 1e-5f);
    float ga = g2w[c];
    a2s[c] = rs * ga;
    d2s[c] = g2b[c] - mu * rs * ga;
  }
  __syncthreads();

  // ===================== PHASE 4: final (own 64 wids) ========================
  for (int i = tid; i < 8192; i += 512) {
    int lw = i >> 7, c = i & 127;
    int wid = b * 1024 + (mc << 6) + lw;
    const float* zp = y1 + (size_t)wid * 1024;
    float zmx = zp[c];
    float zmn = zp[128 + c];
    float az = a2s[c], dz = d2s[c];
    float z = (az >= 0.0f) ? zmx : zmn;
    nf[(size_t)wid * 128 + c] = fmaxf(0.0f, fmaf(z, az, dz));
  }
}

extern "C" void kernel_launch(void* const* d_in, const int* in_sizes, int n_in,
                              void* d_out, int out_size, void* d_ws, size_t ws_size,
                              hipStream_t stream) {
  const float* xyz  = (const float*)d_in[0];
  const float* feat = (const float*)d_in[1];
  const float* w1   = (const float*)d_in[2];
  const float* b1   = (const float*)d_in[3];
  const float* g1w  = (const float*)d_in[4];
  const float* g1b  = (const float*)d_in[5];
  const float* w2   = (const float*)d_in[6];
  const float* b2   = (const float*)d_in[7];
  const float* g2w  = (const float*)d_in[8];
  const float* g2b  = (const float*)d_in[9];
  float* ws = (float*)d_ws;
  float* cent = (float*)d_out;                    // (B,M,3)
  float* nf   = (float*)d_out + BB * MM * 3;      // (B,M,128)
  const float4* pts4 = (const float4*)(ws + PTS4_OFF);
  float* sums1 = ws + SUM1_OFF;
  float* sums2 = ws + SUM2_OFF;
  int*   cnt   = (int*)(ws + CNT_OFF);
  const unsigned short* w2b = (const unsigned short*)(ws + W2B_OFF);
  const unsigned short* w1b = (const unsigned short*)(ws + W1B_OFF);
  const unsigned short* feat16 = (const unsigned short*)(ws + FEAT16_OFF);
  float* y1 = ws + Y1_OFF;

  hipLaunchKernelGGL(fps_init_kernel, dim3(256), dim3(256), 0, stream,
                     xyz, feat, w1, w2, ws, cent);
  hipLaunchKernelGGL(mega_kernel, dim3(256), dim3(512), 0, stream,
                     pts4, xyz, feat16, cent, w1b, b1, w2b, b2,
                     g1w, g1b, g2w, g2b, y1, sums1, sums2, cnt, nf);
}